// Round 12
// baseline (876.504 us; speedup 1.0000x reference)
//
#include <hip/hip_runtime.h>
#include <math.h>

// ---------------------------------------------------------------------------
// MegaCartTensorOut, R12: R11 + tail_light occupancy fix.
// R11 counters: tail_light = 243/285 µs, VGPR 256, occupancy 9.5% — compiler
// greedily hoists across the unrolled 2-node loop when uncapped. True live
// set ~40 regs (unlike R6/R7's monolith), so cap IS safe here:
// __launch_bounds__(256,4) (<=128 VGPR) + #pragma unroll 1 on the node loop.
// Tripwire: WRITE_SIZE must stay ~14 MB (spill detector).
// ---------------------------------------------------------------------------

#define N_CG_FLOATS 438

typedef short s16x8 __attribute__((ext_vector_type(8)));
typedef short s16x4 __attribute__((ext_vector_type(4)));
typedef float f32x4 __attribute__((ext_vector_type(4)));

// pk region (units: shorts, from byte 2048 of ws) — ends at byte 69632
#define PK_BYTE_OFF 2048
#define PK_A1 0       // 16 frags (K=128,N=64)
#define PK_W0 8192    // 8  frags (K=128,N=32), *1/sqrt(128)
#define PK_A2 12288   // 36 frags (K=64, N=288)
#define PK_W1 30720   // 4  frags (K=64, N=32), *0.125
#define PK_W2 32768   // 2  frags (K=32, N=32), *1/sqrt(32)
#define PK_TOTAL 33792

// intermediate buffers start ABOVE the pk region
#define BUF_BASE 131072
// fallback offsets
#define Y0_BYTE_OFF 131072
#define TW8_BYTE_OFF 3331072

__device__ __forceinline__ short f2bf(float f) {
  union { float f; unsigned u; } x; x.f = f;
  unsigned r = (x.u + 0x7FFFu + ((x.u >> 16) & 1u)) >> 16;
  return (short)r;
}
__device__ __forceinline__ float bf2f(unsigned short s) {
  union { unsigned u; float f; } x; x.u = ((unsigned)s) << 16;
  return x.f;
}

// ---------------- CG setup (verified rounds 1-11) ----------------------------

__device__ __forceinline__ double dfact(int n) {
  double r = 1.0;
  for (int i = 2; i <= n; ++i) r *= (double)i;
  return r;
}

__device__ __forceinline__ void u_elem(int l, int i, int j, double& re, double& im) {
  re = 0.0; im = 0.0;
  const int mr = i - l, mc = j - l;
  const double is2 = 0.70710678118654752440;
  if (mr == 0) { if (mc == 0) re = 1.0; }
  else if (mr > 0) {
    if (mc == mr) re = ((mr & 1) ? -1.0 : 1.0) * is2;
    else if (mc == -mr) re = is2;
  } else {
    int m = -mr;
    if (mc == m) im = -(((m & 1) ? -1.0 : 1.0)) * is2;
    else if (mc == -m) im = is2;
  }
}

__global__ void setup_cg_par(float* __restrict__ ws) {
  const int LAs[12] = {0, 1, 2, 1, 2, 0, 2, 1, 2, 1, 1, 1};
  const int LBs[12] = {0, 1, 2, 1, 2, 2, 0, 1, 2, 1, 1, 1};
  const int LOs[12] = {0, 0, 0, 1, 1, 2, 2, 2, 2, 0, 1, 2};
  const int OFF[12] = {0, 1, 10, 35, 62, 137, 162, 187, 232, 357, 366, 393};

  const int blk = blockIdx.x;
  const int l1 = LAs[blk], l2 = LBs[blk], l3 = LOs[blk];
  const double scale = (blk >= 9) ? sqrt(2.0 * l3 + 1.0) : 1.0;
  const int n1 = 2 * l1 + 1, n2 = 2 * l2 + 1, n3 = 2 * l3 + 1;
  const int nel = n1 * n2 * n3;
  const int t = threadIdx.x;

  __shared__ double Cs[125];
  __shared__ double Rre[125], Rim[125];
  __shared__ double s_inv;
  __shared__ int s_useRe;

  if (t < nel) {
    const int i3 = t % n3, i2 = (t / n3) % n2, i1 = t / (n3 * n2);
    const int m1 = i1 - l1, m2 = i2 - l2, m3 = i3 - l3;
    double val = 0.0;
    if (m1 + m2 == m3) {
      double pre = sqrt((2.0 * l3 + 1.0) * dfact(l1 + l2 - l3) * dfact(l1 - l2 + l3) *
                        dfact(-l1 + l2 + l3) / dfact(l1 + l2 + l3 + 1));
      pre *= sqrt(dfact(l3 + m3) * dfact(l3 - m3) * dfact(l1 - m1) * dfact(l1 + m1) *
                  dfact(l2 - m2) * dfact(l2 + m2));
      double s = 0.0;
      for (int k = 0; k <= l1 + l2 - l3; ++k) {
        int d1 = l1 + l2 - l3 - k, d2 = l1 - m1 - k, d3 = l2 + m2 - k;
        int d4 = l3 - l2 + m1 + k, d5 = l3 - l1 - m2 + k;
        if (d1 < 0 || d2 < 0 || d3 < 0 || d4 < 0 || d5 < 0) continue;
        double prod = dfact(k) * dfact(d1) * dfact(d2) * dfact(d3) * dfact(d4) * dfact(d5);
        s += ((k & 1) ? -1.0 : 1.0) / prod;
      }
      val = pre * s;
    }
    Cs[t] = val;
  }
  __syncthreads();

  if (t < nel) {
    const int c = t % n3, bb = (t / n3) % n2, a = t / (n3 * n2);
    double sr_ = 0.0, si_ = 0.0;
    for (int m = 0; m < n1; ++m) {
      double u1r, u1i;
      u_elem(l1, a, m, u1r, u1i);
      if (u1r == 0.0 && u1i == 0.0) continue;
      for (int nn = 0; nn < n2; ++nn) {
        double u2r, u2i;
        u_elem(l2, bb, nn, u2r, u2i);
        double t12r = u1r * u2r - u1i * u2i;
        double t12i = u1r * u2i + u1i * u2r;
        if (t12r == 0.0 && t12i == 0.0) continue;
        for (int o = 0; o < n3; ++o) {
          double cgv = Cs[(m * n2 + nn) * n3 + o];
          if (cgv == 0.0) continue;
          double u3r, u3i;
          u_elem(l3, c, o, u3r, u3i);
          sr_ += (t12r * u3r + t12i * u3i) * cgv;
          si_ += (t12i * u3r - t12r * u3i) * cgv;
        }
      }
    }
    Rre[t] = sr_;
    Rim[t] = si_;
  }
  __syncthreads();

  if (t == 0) {
    double maxRe = 0.0, maxIm = 0.0;
    for (int e = 0; e < nel; ++e) {
      maxRe = fmax(maxRe, fabs(Rre[e]));
      maxIm = fmax(maxIm, fabs(Rim[e]));
    }
    int useRe = (maxRe >= maxIm) ? 1 : 0;
    double nrm = 0.0;
    for (int e = 0; e < nel; ++e) {
      double vv = useRe ? Rre[e] : Rim[e];
      nrm += vv * vv;
    }
    s_useRe = useRe;
    s_inv = scale / sqrt(nrm);
  }
  __syncthreads();

  if (t < nel) {
    double vv = s_useRe ? Rre[t] : Rim[t];
    ws[OFF[blk] + t] = (float)(vv * s_inv);
  }
}

// ---------------- weight fragment packing ------------------------------------
__global__ void pack_weights(const float* __restrict__ A1, const float* __restrict__ W0,
                             const float* __restrict__ A2, const float* __restrict__ W1,
                             const float* __restrict__ W2, float* __restrict__ ws) {
  unsigned short* pk = (unsigned short*)((char*)ws + PK_BYTE_OFF);
  int e = blockIdx.x * 256 + threadIdx.x;
  if (e >= PK_TOTAL) return;
  const float* src;
  int Ncols, off;
  float scale;
  if (e < PK_W0)      { src = A1; Ncols = 64;  off = PK_A1; scale = 1.f; }
  else if (e < PK_A2) { src = W0; Ncols = 32;  off = PK_W0; scale = 0.08838834764831845f; }
  else if (e < PK_W1) { src = A2; Ncols = 288; off = PK_A2; scale = 1.f; }
  else if (e < PK_W2) { src = W1; Ncols = 32;  off = PK_W1; scale = 0.125f; }
  else                { src = W2; Ncols = 32;  off = PK_W2; scale = 0.17677669529663687f; }
  int local = e - off;
  int frag = local >> 9;
  int l = (local >> 3) & 63;
  int j = local & 7;
  int ntn = Ncols >> 4;
  int kt = frag / ntn, nt = frag - kt * ntn;
  int k = kt * 32 + 8 * (l >> 4) + j;
  int c = nt * 16 + (l & 15);
  pk[e] = (unsigned short)f2bf(src[k * Ncols + c] * scale);
}

// ---------------- shared helpers ---------------------------------------------

__device__ __forceinline__ s16x8 cvt8(const float* __restrict__ g) {
  float4 a = *(const float4*)g;
  float4 b = *(const float4*)(g + 4);
  s16x8 r;
  r[0] = f2bf(a.x); r[1] = f2bf(a.y); r[2] = f2bf(a.z); r[3] = f2bf(a.w);
  r[4] = f2bf(b.x); r[5] = f2bf(b.y); r[6] = f2bf(b.z); r[7] = f2bf(b.w);
  return r;
}

__device__ __forceinline__ void sw_wr8(char* sm, int base, int strideB, int r, int c0, s16x8 v) {
  int byte = base + r * strideB + c0 * 2;
  byte ^= (r & 7) << 4;
  *(s16x8*)(sm + byte) = v;
}
__device__ __forceinline__ s16x8 sw_lda16(const char* sm, int base, int strideB, int k0,
                                          int lane) {
  int r = lane & 15;
  int byte = base + r * strideB + (k0 + 8 * (lane >> 4)) * 2;
  byte ^= (r & 7) << 4;
  return *(const s16x8*)(sm + byte);
}

template <int LA, int LB, int LO>
__device__ __forceinline__ void tp_accum(const float* __restrict__ R, float w,
                                         const float* xa, const float* xb, float* sph) {
  constexpr int NA = 2 * LA + 1, NB = 2 * LB + 1, NC = 2 * LO + 1;
#pragma unroll
  for (int a = 0; a < NA; ++a) {
#pragma unroll
    for (int b = 0; b < NB; ++b) {
      float xab = xa[a] * xb[b] * w;
#pragma unroll
      for (int c = 0; c < NC; ++c) sph[c] = fmaf(xab, R[(a * NB + b) * NC + c], sph[c]);
    }
  }
}

// ================== FULL PATH: kernel A (all GEMMs) ==========================

#define FA_XS 0      // [16][128] bf16, 256B rows, swz
#define FA_SP 4096   // [16][128] bf16, 256B rows, swz
#define FA_H  8192   // [16][64]  bf16, 128B rows, swz
#define FA_P1 10240  // 3 planes x [16] rows x 128B, swz
#define FA_P2 16384  // 5 planes x [16] rows x 64B, swz
#define FA_SMEM 21504

__global__ __launch_bounds__(256) void gemm_full(
    const float* __restrict__ xs_g, const float* __restrict__ sp_g,
    const float* __restrict__ b1, const float* __restrict__ b2,
    const float* __restrict__ ws, unsigned short* __restrict__ yall,
    unsigned short* __restrict__ tww, int N) {
  __shared__ char sm[FA_SMEM];
  const unsigned short* pk = (const unsigned short*)((const char*)ws + PK_BYTE_OFF);

  const int t = threadIdx.x;
  const int b0 = blockIdx.x * 16;
  const int lane = t & 63;
  const int wid = t >> 6;

  // ---- staging: xs + sp0 (b128 swz writes)
  {
    int n = t >> 4, c0 = (t & 15) * 8;
    long nn = min((long)(b0 + n), (long)N - 1);
    sw_wr8(sm, FA_XS, 256, n, c0, cvt8(xs_g + nn * 128 + c0));
    sw_wr8(sm, FA_SP, 256, n, c0, cvt8(sp_g + nn * 480 + c0));
  }
  // ---- staging: l1 planes, chunk-local (4 u's per thread)
  {
    int n = t >> 4, uc = t & 15;
    long nn = min((long)(b0 + n), (long)N - 1);
    const float* g = sp_g + nn * 480 + 128 + uc * 12;
    float4 a0 = *(const float4*)(g), a1 = *(const float4*)(g + 4), a2 = *(const float4*)(g + 8);
    float fl[12] = {a0.x, a0.y, a0.z, a0.w, a1.x, a1.y, a1.z, a1.w, a2.x, a2.y, a2.z, a2.w};
#pragma unroll
    for (int m = 0; m < 3; ++m) {
      s16x4 e;
#pragma unroll
      for (int j = 0; j < 4; ++j) e[j] = f2bf(fl[j * 3 + m]);
      int byte = FA_P1 + m * 2048 + n * 128 + uc * 8;
      byte ^= (n & 7) << 4;
      *(s16x4*)(sm + byte) = e;
    }
  }
  // ---- staging: l2 planes (threads < 128, 4 u's per thread)
  if (t < 128) {
    int n = t >> 3, uc = t & 7;
    long nn = min((long)(b0 + n), (long)N - 1);
    const float* g = sp_g + nn * 480 + 320 + uc * 20;
    float4 a0 = *(const float4*)(g), a1 = *(const float4*)(g + 4), a2 = *(const float4*)(g + 8),
           a3 = *(const float4*)(g + 12), a4 = *(const float4*)(g + 16);
    float fl[20] = {a0.x, a0.y, a0.z, a0.w, a1.x, a1.y, a1.z, a1.w, a2.x, a2.y,
                    a2.z, a2.w, a3.x, a3.y, a3.z, a3.w, a4.x, a4.y, a4.z, a4.w};
#pragma unroll
    for (int m = 0; m < 5; ++m) {
      s16x4 e;
#pragma unroll
      for (int j = 0; j < 4; ++j) e[j] = f2bf(fl[j * 5 + m]);
      int byte = FA_P2 + m * 1024 + n * 64 + uc * 8;
      byte ^= (n & 7) << 4;
      *(s16x4*)(sm + byte) = e;
    }
  }
  __syncthreads();

  // ---- h = silu(xs @ A1 + b1); wave wid owns nt=wid -> LDS
  {
    f32x4 acc = {0.f, 0.f, 0.f, 0.f};
#pragma unroll
    for (int kt = 0; kt < 4; ++kt) {
      s16x8 a = sw_lda16(sm, FA_XS, 256, kt * 32, lane);
      s16x8 b = *(const s16x8*)(pk + PK_A1 + (((kt << 2) + wid) * 64 + lane) * 8);
      acc = __builtin_amdgcn_mfma_f32_16x16x32_bf16(a, b, acc, 0, 0, 0);
    }
    const int col = wid * 16 + (lane & 15);
    const int r0 = (lane >> 4) * 4;
    const float bb = b1[col];
#pragma unroll
    for (int q = 0; q < 4; ++q) {
      float hv = acc[q] + bb;
      hv = hv / (1.f + __expf(-hv));
      int r = r0 + q;
      int byte = FA_H + r * 128 + col * 2;
      byte ^= (r & 7) << 4;
      *(short*)(sm + byte) = f2bf(hv);
    }
  }

  const int r0 = (lane >> 4) * 4;
  // ---- y0 tiles (waves 0,1) -> yall cols 0..31
  if (wid < 2) {
    f32x4 acc = {0.f, 0.f, 0.f, 0.f};
#pragma unroll
    for (int kt = 0; kt < 4; ++kt) {
      s16x8 a = sw_lda16(sm, FA_SP, 256, kt * 32, lane);
      s16x8 b = *(const s16x8*)(pk + PK_W0 + (((kt << 1) + wid) * 64 + lane) * 8);
      acc = __builtin_amdgcn_mfma_f32_16x16x32_bf16(a, b, acc, 0, 0, 0);
    }
    const int col = wid * 16 + (lane & 15);
#pragma unroll
    for (int q = 0; q < 4; ++q)
      yall[(long)(b0 + r0 + q) * 288 + col] = (unsigned short)f2bf(acc[q]);
  }
  // ---- y1 tiles (6) -> yall cols 32..127
  for (int tl = wid; tl < 6; tl += 4) {
    const int m = tl >> 1, nt = tl & 1;
    f32x4 acc = {0.f, 0.f, 0.f, 0.f};
#pragma unroll
    for (int kt = 0; kt < 2; ++kt) {
      s16x8 a = sw_lda16(sm, FA_P1 + m * 2048, 128, kt * 32, lane);
      s16x8 b = *(const s16x8*)(pk + PK_W1 + (((kt << 1) + nt) * 64 + lane) * 8);
      acc = __builtin_amdgcn_mfma_f32_16x16x32_bf16(a, b, acc, 0, 0, 0);
    }
    const int col = 32 + m * 32 + nt * 16 + (lane & 15);
#pragma unroll
    for (int q = 0; q < 4; ++q)
      yall[(long)(b0 + r0 + q) * 288 + col] = (unsigned short)f2bf(acc[q]);
  }
  // ---- y2 tiles (10) -> yall cols 128..287
  for (int tl = wid; tl < 10; tl += 4) {
    const int m = tl >> 1, nt = tl & 1;
    f32x4 acc = {0.f, 0.f, 0.f, 0.f};
    {
      s16x8 a = sw_lda16(sm, FA_P2 + m * 1024, 64, 0, lane);
      s16x8 b = *(const s16x8*)(pk + PK_W2 + (nt * 64 + lane) * 8);
      acc = __builtin_amdgcn_mfma_f32_16x16x32_bf16(a, b, acc, 0, 0, 0);
    }
    const int col = 128 + m * 32 + nt * 16 + (lane & 15);
#pragma unroll
    for (int q = 0; q < 4; ++q)
      yall[(long)(b0 + r0 + q) * 288 + col] = (unsigned short)f2bf(acc[q]);
  }
  __syncthreads();  // H ready

  // ---- A2 tiles: tw = h @ A2 + b2 -> tww
  for (int tl = wid; tl < 18; tl += 4) {
    f32x4 acc = {0.f, 0.f, 0.f, 0.f};
#pragma unroll
    for (int kt = 0; kt < 2; ++kt) {
      s16x8 a = sw_lda16(sm, FA_H, 128, kt * 32, lane);
      s16x8 b = *(const s16x8*)(pk + PK_A2 + ((kt * 18 + tl) * 64 + lane) * 8);
      acc = __builtin_amdgcn_mfma_f32_16x16x32_bf16(a, b, acc, 0, 0, 0);
    }
    const int col = tl * 16 + (lane & 15);
    const float bb = b2[col];
#pragma unroll
    for (int q = 0; q < 4; ++q)
      tww[(long)(b0 + r0 + q) * 288 + col] = (unsigned short)f2bf(acc[q] + bb);
  }
}

// ================== FULL PATH: kernel B (light tail) =========================
// __launch_bounds__(256,4): cap 128 VGPR. True live set ~40 regs (small
// kernel) so no spill risk; R11's uncapped build hit 256 VGPR / 9.5% occ.

__global__ __launch_bounds__(256, 4) void tail_light(
    const int* __restrict__ batch, const float* __restrict__ p0,
    const float* __restrict__ p1, const float* __restrict__ p2,
    const float* __restrict__ ws, const unsigned short* __restrict__ yall,
    const unsigned short* __restrict__ tww, float* __restrict__ out, int N) {
  __shared__ __align__(16) float cg[N_CG_FLOATS];
  const int t = threadIdx.x;
  const int b0 = blockIdx.x * 16;
  for (int i = t; i < N_CG_FLOATS; i += 256) cg[i] = ws[i];
  __syncthreads();

  const int v = t & 31;
  const int sl = t >> 5;
  const float invs32 = 0.17677669529663687f;
  const float k0c = invs32 / 3.0f;
  const float k1c = 1.7320508075688772f * invs32 / 2.0f;
  const float k2c = 2.23606797749979f * invs32 / 4.0f;
  const float c0 = k0c * p0[0], c1 = k0c * p0[1], c2 = k0c * p0[2];
  const float c3 = k1c * p1[0], c4 = k1c * p1[1];
  const float c5 = k2c * p2[0], c6 = k2c * p2[1], c7 = k2c * p2[2], c8 = k2c * p2[3];
  const float* qb0 = cg + 357;
  const float* qb1 = cg + 366;
  const float* qb2 = cg + 393;

#pragma unroll 1
  for (int r = 0; r < 2; ++r) {
    const int n = b0 + sl + 8 * r;
    const long nn = min((long)n, (long)N - 1);
    const unsigned short* yb = yall + nn * 288;
    const unsigned short* tb = tww + nn * 288;

    const float y0v = bf2f(yb[v]);
    float y1[3], y2[5];
#pragma unroll
    for (int m = 0; m < 3; ++m) y1[m] = bf2f(yb[32 + m * 32 + v]);
#pragma unroll
    for (int m = 0; m < 5; ++m) y2[m] = bf2f(yb[128 + m * 32 + v]);

    float s0 = y0v * y0v;
    float s1 = y1[0] * y1[0] + y1[1] * y1[1] + y1[2] * y1[2];
    float s2 = 0.f;
#pragma unroll
    for (int m = 0; m < 5; ++m) s2 = fmaf(y2[m], y2[m], s2);
#pragma unroll
    for (int msk = 16; msk >= 1; msk >>= 1) {
      s0 += __shfl_xor(s0, msk);
      s1 += __shfl_xor(s1, msk);
      s2 += __shfl_xor(s2, msk);
    }
    const float i0 = 1.0f / sqrtf(s0 * (1.0f / 32.0f) + 1e-5f);
    const float i1 = 1.0f / sqrtf(s1 * (1.0f / 96.0f) + 1e-5f);
    const float i2 = 1.0f / sqrtf(s2 * (1.0f / 160.0f) + 1e-5f);
    float xs0[1] = {y0v * i0};
    float xs1[3], xs2[5];
#pragma unroll
    for (int m = 0; m < 3; ++m) xs1[m] = y1[m] * i1;
#pragma unroll
    for (int m = 0; m < 5; ++m) xs2[m] = y2[m] * i2;

    float w9[9];
#pragma unroll
    for (int i = 0; i < 9; ++i) w9[i] = bf2f(tb[i * 32 + v]);

    float sph0[1] = {0.f};
    float sph1[3] = {0.f, 0.f, 0.f};
    float sph2[5] = {0.f, 0.f, 0.f, 0.f, 0.f};
    tp_accum<0, 0, 0>(cg + 0,   w9[0] * c0, xs0, xs0, sph0);
    tp_accum<1, 1, 0>(cg + 1,   w9[1] * c1, xs1, xs1, sph0);
    tp_accum<2, 2, 0>(cg + 10,  w9[2] * c2, xs2, xs2, sph0);
    tp_accum<1, 1, 1>(cg + 35,  w9[3] * c3, xs1, xs1, sph1);
    tp_accum<2, 2, 1>(cg + 62,  w9[4] * c4, xs2, xs2, sph1);
    tp_accum<0, 2, 2>(cg + 137, w9[5] * c5, xs0, xs2, sph2);
    tp_accum<2, 0, 2>(cg + 162, w9[6] * c6, xs2, xs0, sph2);
    tp_accum<1, 1, 2>(cg + 187, w9[7] * c7, xs1, xs1, sph2);
    tp_accum<2, 2, 2>(cg + 232, w9[8] * c8, xs2, xs2, sph2);

#pragma unroll
    for (int msk = 16; msk >= 1; msk >>= 1) {
      sph0[0] += __shfl_xor(sph0[0], msk);
#pragma unroll
      for (int m = 0; m < 3; ++m) sph1[m] += __shfl_xor(sph1[m], msk);
#pragma unroll
      for (int m = 0; m < 5; ++m) sph2[m] += __shfl_xor(sph2[m], msk);
    }

    if (v == 0 && n < N) {
      float* og = out + (long)batch[n] * 9;
#pragma unroll
      for (int i = 0; i < 3; ++i) {
#pragma unroll
        for (int j = 0; j < 3; ++j) {
          float val = sph0[0] * qb0[i * 3 + j];
#pragma unroll
          for (int m = 0; m < 3; ++m) val = fmaf(sph1[m], qb1[(i * 3 + j) * 3 + m], val);
#pragma unroll
          for (int m = 0; m < 5; ++m) val = fmaf(sph2[m], qb2[(i * 3 + j) * 5 + m], val);
          atomicAdd(&og[((i + 1) % 3) * 3 + ((j + 1) % 3)], val);
        }
      }
    }
  }
}

// ================== FALLBACK PATH: exact R8 kernels ==========================

#define A_XS_OFF 0
#define A_SP_OFF 4096
#define A_H_OFF 8192
#define A_SMEM 10240

__global__ __launch_bounds__(256) void gemm_r8(
    const float* __restrict__ xs_g, const float* __restrict__ sp_g,
    const float* __restrict__ b1, const float* __restrict__ b2,
    float* __restrict__ ws, int N) {
  __shared__ char sm[A_SMEM];
  const unsigned short* pk = (const unsigned short*)((const char*)ws + PK_BYTE_OFF);
  unsigned short* y0w = (unsigned short*)((char*)ws + Y0_BYTE_OFF);
  unsigned short* tww = (unsigned short*)((char*)ws + TW8_BYTE_OFF);

  const int t = threadIdx.x;
  const int b0 = blockIdx.x * 16;
  const int lane = t & 63;
  const int wid = t >> 6;

  {
    int n = t >> 4, c0 = (t & 15) * 8;
    long nn = min((long)(b0 + n), (long)N - 1);
    sw_wr8(sm, A_XS_OFF, 256, n, c0, cvt8(xs_g + nn * 128 + c0));
    sw_wr8(sm, A_SP_OFF, 256, n, c0, cvt8(sp_g + nn * 480 + c0));
  }
  __syncthreads();

  {
    f32x4 acc = {0.f, 0.f, 0.f, 0.f};
#pragma unroll
    for (int kt = 0; kt < 4; ++kt) {
      s16x8 a = sw_lda16(sm, A_XS_OFF, 256, kt * 32, lane);
      s16x8 b = *(const s16x8*)(pk + PK_A1 + (((kt << 2) + wid) * 64 + lane) * 8);
      acc = __builtin_amdgcn_mfma_f32_16x16x32_bf16(a, b, acc, 0, 0, 0);
    }
    const int col = wid * 16 + (lane & 15);
    const int r0 = (lane >> 4) * 4;
    const float bb = b1[col];
#pragma unroll
    for (int q = 0; q < 4; ++q) {
      float hv = acc[q] + bb;
      hv = hv / (1.f + __expf(-hv));
      int r = r0 + q;
      int byte = A_H_OFF + r * 128 + col * 2;
      byte ^= (r & 7) << 4;
      *(short*)(sm + byte) = f2bf(hv);
    }
  }

  if (wid >= 2) {
    f32x4 acc = {0.f, 0.f, 0.f, 0.f};
#pragma unroll
    for (int kt = 0; kt < 4; ++kt) {
      s16x8 a = sw_lda16(sm, A_SP_OFF, 256, kt * 32, lane);
      s16x8 b = *(const s16x8*)(pk + PK_W0 + (((kt << 1) + (wid - 2)) * 64 + lane) * 8);
      acc = __builtin_amdgcn_mfma_f32_16x16x32_bf16(a, b, acc, 0, 0, 0);
    }
    const int col = (wid - 2) * 16 + (lane & 15);
    const int r0 = (lane >> 4) * 4;
#pragma unroll
    for (int q = 0; q < 4; ++q)
      y0w[(long)(b0 + r0 + q) * 32 + col] = (unsigned short)f2bf(acc[q]);
  }
  __syncthreads();

#pragma unroll
  for (int i = 0; i < 5; ++i) {
    const int nt = wid + 4 * i;
    if (nt < 18) {
      f32x4 acc = {0.f, 0.f, 0.f, 0.f};
#pragma unroll
      for (int kt = 0; kt < 2; ++kt) {
        s16x8 a = sw_lda16(sm, A_H_OFF, 128, kt * 32, lane);
        s16x8 b = *(const s16x8*)(pk + PK_A2 + ((kt * 18 + nt) * 64 + lane) * 8);
        acc = __builtin_amdgcn_mfma_f32_16x16x32_bf16(a, b, acc, 0, 0, 0);
      }
      const int col = nt * 16 + (lane & 15);
      const int r0 = (lane >> 4) * 4;
      const float bb = b2[col];
#pragma unroll
      for (int q = 0; q < 4; ++q)
        tww[(long)(b0 + r0 + q) * 288 + col] = (unsigned short)f2bf(acc[q] + bb);
    }
  }
}

__global__ __launch_bounds__(256) void tail_r8(
    const float* __restrict__ sp_g, const int* __restrict__ batch,
    const float* __restrict__ W1g, const float* __restrict__ W2g,
    const float* __restrict__ p0, const float* __restrict__ p1,
    const float* __restrict__ p2, const float* __restrict__ ws,
    float* __restrict__ out, int N) {
  __shared__ __align__(16) float cg[N_CG_FLOATS];
  __shared__ __align__(16) float sp12[16 * 352];
  __shared__ __align__(16) float w12[3072];

  const unsigned short* y0w = (const unsigned short*)((const char*)ws + Y0_BYTE_OFF);
  const unsigned short* tww = (const unsigned short*)((const char*)ws + TW8_BYTE_OFF);

  const int t = threadIdx.x;
  const int b0 = blockIdx.x * 16;
  const int nb = min(16, N - b0);

  for (int i = t; i < N_CG_FLOATS; i += 256) cg[i] = ws[i];
  {
    float4* d = (float4*)sp12;
    for (int i = t; i < 16 * 88; i += 256) {
      int n = i / 88, j = i - n * 88;
      long nn = min((long)(b0 + n), (long)N - 1);
      d[i] = *(const float4*)(sp_g + nn * 480 + 128 + j * 4);
    }
    float4* w4 = (float4*)w12;
    for (int i = t; i < 768; i += 256) {
      float4 f;
      float scl;
      if (i < 512) { f = ((const float4*)W1g)[i]; scl = 0.125f; }
      else         { f = ((const float4*)W2g)[i - 512]; scl = 0.17677669529663687f; }
      float4 o;
      o.x = f.x * scl; o.y = f.y * scl; o.z = f.z * scl; o.w = f.w * scl;
      w4[i] = o;
    }
  }
  __syncthreads();

  const int v = t & 31;
  const int sl = t >> 5;
  const bool actA = (sl < nb);
  const bool actB = (sl + 8 < nb);
  const int rA = actA ? sl : 0;
  const int rB = actB ? (sl + 8) : 0;

  const float4* sA4 = (const float4*)(sp12 + rA * 352);
  const float4* sB4 = (const float4*)(sp12 + rB * 352);

  float y1A[3] = {0.f, 0.f, 0.f}, y1B[3] = {0.f, 0.f, 0.f};
#pragma unroll 4
  for (int q = 0; q < 16; ++q) {
    float4 a0 = sA4[q * 3], a1 = sA4[q * 3 + 1], a2 = sA4[q * 3 + 2];
    float4 c0_ = sB4[q * 3], c1_ = sB4[q * 3 + 1], c2_ = sB4[q * 3 + 2];
    float eA[12] = {a0.x, a0.y, a0.z, a0.w, a1.x, a1.y, a1.z, a1.w, a2.x, a2.y, a2.z, a2.w};
    float eB[12] = {c0_.x, c0_.y, c0_.z, c0_.w, c1_.x, c1_.y, c1_.z, c1_.w, c2_.x, c2_.y, c2_.z, c2_.w};
    float w = 0.f;
#pragma unroll
    for (int e = 0; e < 12; ++e) {
      if (e % 3 == 0) w = w12[(q * 4 + e / 3) * 32 + v];
      y1A[e % 3] = fmaf(eA[e], w, y1A[e % 3]);
      y1B[e % 3] = fmaf(eB[e], w, y1B[e % 3]);
    }
  }

  float y2A[5] = {0.f, 0.f, 0.f, 0.f, 0.f}, y2B[5] = {0.f, 0.f, 0.f, 0.f, 0.f};
#pragma unroll 2
  for (int q = 0; q < 8; ++q) {
    float4 a0 = sA4[48 + q * 5], a1 = sA4[48 + q * 5 + 1], a2 = sA4[48 + q * 5 + 2],
           a3 = sA4[48 + q * 5 + 3], a4 = sA4[48 + q * 5 + 4];
    float4 c0_ = sB4[48 + q * 5], c1_ = sB4[48 + q * 5 + 1], c2_ = sB4[48 + q * 5 + 2],
           c3_ = sB4[48 + q * 5 + 3], c4_ = sB4[48 + q * 5 + 4];
    float eA[20] = {a0.x, a0.y, a0.z, a0.w, a1.x, a1.y, a1.z, a1.w, a2.x, a2.y,
                    a2.z, a2.w, a3.x, a3.y, a3.z, a3.w, a4.x, a4.y, a4.z, a4.w};
    float eB[20] = {c0_.x, c0_.y, c0_.z, c0_.w, c1_.x, c1_.y, c1_.z, c1_.w, c2_.x, c2_.y,
                    c2_.z, c2_.w, c3_.x, c3_.y, c3_.z, c3_.w, c4_.x, c4_.y, c4_.z, c4_.w};
    float w = 0.f;
#pragma unroll
    for (int e = 0; e < 20; ++e) {
      if (e % 5 == 0) w = w12[2048 + (q * 4 + e / 5) * 32 + v];
      y2A[e % 5] = fmaf(eA[e], w, y2A[e % 5]);
      y2B[e % 5] = fmaf(eB[e], w, y2B[e % 5]);
    }
  }

  const float y0A = bf2f(y0w[(long)(b0 + rA) * 32 + v]);
  const float y0B = bf2f(y0w[(long)(b0 + rB) * 32 + v]);

  float s0A = y0A * y0A, s0B = y0B * y0B;
  float s1A = y1A[0] * y1A[0] + y1A[1] * y1A[1] + y1A[2] * y1A[2];
  float s1B = y1B[0] * y1B[0] + y1B[1] * y1B[1] + y1B[2] * y1B[2];
  float s2A = 0.f, s2B = 0.f;
#pragma unroll
  for (int m = 0; m < 5; ++m) { s2A = fmaf(y2A[m], y2A[m], s2A); s2B = fmaf(y2B[m], y2B[m], s2B); }
#pragma unroll
  for (int msk = 16; msk >= 1; msk >>= 1) {
    s0A += __shfl_xor(s0A, msk); s0B += __shfl_xor(s0B, msk);
    s1A += __shfl_xor(s1A, msk); s1B += __shfl_xor(s1B, msk);
    s2A += __shfl_xor(s2A, msk); s2B += __shfl_xor(s2B, msk);
  }
  const float i0A = 1.0f / sqrtf(s0A * (1.0f / 32.0f) + 1e-5f);
  const float i0B = 1.0f / sqrtf(s0B * (1.0f / 32.0f) + 1e-5f);
  const float i1A = 1.0f / sqrtf(s1A * (1.0f / 96.0f) + 1e-5f);
  const float i1B = 1.0f / sqrtf(s1B * (1.0f / 96.0f) + 1e-5f);
  const float i2A = 1.0f / sqrtf(s2A * (1.0f / 160.0f) + 1e-5f);
  const float i2B = 1.0f / sqrtf(s2B * (1.0f / 160.0f) + 1e-5f);

  float xs0A[1] = {y0A * i0A}, xs0B[1] = {y0B * i0B};
  float xs1A[3], xs1B[3], xs2A[5], xs2B[5];
#pragma unroll
  for (int m = 0; m < 3; ++m) { xs1A[m] = y1A[m] * i1A; xs1B[m] = y1B[m] * i1B; }
#pragma unroll
  for (int m = 0; m < 5; ++m) { xs2A[m] = y2A[m] * i2A; xs2B[m] = y2B[m] * i2B; }

  float wA[9], wB[9];
#pragma unroll
  for (int i = 0; i < 9; ++i) {
    wA[i] = bf2f(tww[(long)(b0 + rA) * 288 + i * 32 + v]);
    wB[i] = bf2f(tww[(long)(b0 + rB) * 288 + i * 32 + v]);
  }

  const float invs32 = 0.17677669529663687f;
  const float k0c = invs32 / 3.0f;
  const float k1c = 1.7320508075688772f * invs32 / 2.0f;
  const float k2c = 2.23606797749979f * invs32 / 4.0f;
  const float c0 = k0c * p0[0], c1 = k0c * p0[1], c2 = k0c * p0[2];
  const float c3 = k1c * p1[0], c4 = k1c * p1[1];
  const float c5 = k2c * p2[0], c6 = k2c * p2[1], c7 = k2c * p2[2], c8 = k2c * p2[3];

  float sph0A[1] = {0.f}, sph1A[3] = {0.f, 0.f, 0.f}, sph2A[5] = {0.f, 0.f, 0.f, 0.f, 0.f};
  float sph0B[1] = {0.f}, sph1B[3] = {0.f, 0.f, 0.f}, sph2B[5] = {0.f, 0.f, 0.f, 0.f, 0.f};

  tp_accum<0, 0, 0>(cg + 0,   wA[0] * c0, xs0A, xs0A, sph0A);
  tp_accum<0, 0, 0>(cg + 0,   wB[0] * c0, xs0B, xs0B, sph0B);
  tp_accum<1, 1, 0>(cg + 1,   wA[1] * c1, xs1A, xs1A, sph0A);
  tp_accum<1, 1, 0>(cg + 1,   wB[1] * c1, xs1B, xs1B, sph0B);
  tp_accum<2, 2, 0>(cg + 10,  wA[2] * c2, xs2A, xs2A, sph0A);
  tp_accum<2, 2, 0>(cg + 10,  wB[2] * c2, xs2B, xs2B, sph0B);
  tp_accum<1, 1, 1>(cg + 35,  wA[3] * c3, xs1A, xs1A, sph1A);
  tp_accum<1, 1, 1>(cg + 35,  wB[3] * c3, xs1B, xs1B, sph1B);
  tp_accum<2, 2, 1>(cg + 62,  wA[4] * c4, xs2A, xs2A, sph1A);
  tp_accum<2, 2, 1>(cg + 62,  wB[4] * c4, xs2B, xs2B, sph1B);
  tp_accum<0, 2, 2>(cg + 137, wA[5] * c5, xs0A, xs2A, sph2A);
  tp_accum<0, 2, 2>(cg + 137, wB[5] * c5, xs0B, xs2B, sph2B);
  tp_accum<2, 0, 2>(cg + 162, wA[6] * c6, xs2A, xs0A, sph2A);
  tp_accum<2, 0, 2>(cg + 162, wB[6] * c6, xs2B, xs0B, sph2B);
  tp_accum<1, 1, 2>(cg + 187, wA[7] * c7, xs1A, xs1A, sph2A);
  tp_accum<1, 1, 2>(cg + 187, wB[7] * c7, xs1B, xs1B, sph2B);
  tp_accum<2, 2, 2>(cg + 232, wA[8] * c8, xs2A, xs2A, sph2A);
  tp_accum<2, 2, 2>(cg + 232, wB[8] * c8, xs2B, xs2B, sph2B);

#pragma unroll
  for (int msk = 16; msk >= 1; msk >>= 1) {
    sph0A[0] += __shfl_xor(sph0A[0], msk);
    sph0B[0] += __shfl_xor(sph0B[0], msk);
#pragma unroll
    for (int m = 0; m < 3; ++m) {
      sph1A[m] += __shfl_xor(sph1A[m], msk);
      sph1B[m] += __shfl_xor(sph1B[m], msk);
    }
#pragma unroll
    for (int m = 0; m < 5; ++m) {
      sph2A[m] += __shfl_xor(sph2A[m], msk);
      sph2B[m] += __shfl_xor(sph2B[m], msk);
    }
  }

  if (v == 0) {
    const float* qb0 = cg + 357;
    const float* qb1 = cg + 366;
    const float* qb2 = cg + 393;
#pragma unroll
    for (int nd = 0; nd < 2; ++nd) {
      const bool act = nd ? actB : actA;
      if (!act) continue;
      const int n = b0 + (nd ? (sl + 8) : sl);
      const float* s0p = nd ? sph0B : sph0A;
      const float* s1p = nd ? sph1B : sph1A;
      const float* s2p = nd ? sph2B : sph2A;
      float* og = out + (long)batch[n] * 9;
#pragma unroll
      for (int i = 0; i < 3; ++i) {
#pragma unroll
        for (int j = 0; j < 3; ++j) {
          float val = s0p[0] * qb0[i * 3 + j];
#pragma unroll
          for (int m = 0; m < 3; ++m) val = fmaf(s1p[m], qb1[(i * 3 + j) * 3 + m], val);
#pragma unroll
          for (int m = 0; m < 5; ++m) val = fmaf(s2p[m], qb2[(i * 3 + j) * 5 + m], val);
          atomicAdd(&og[((i + 1) % 3) * 3 + ((j + 1) % 3)], val);
        }
      }
    }
  }
}

// ---------------------------------------------------------------------------

extern "C" void kernel_launch(void* const* d_in, const int* in_sizes, int n_in,
                              void* d_out, int out_size, void* d_ws, size_t ws_size,
                              hipStream_t stream) {
  const float* x_scalar = (const float*)d_in[0];
  const float* x_sph    = (const float*)d_in[1];
  const int*   batch    = (const int*)d_in[2];
  const float* W0 = (const float*)d_in[4];
  const float* W1 = (const float*)d_in[5];
  const float* W2 = (const float*)d_in[6];
  const float* A1 = (const float*)d_in[7];
  const float* b1 = (const float*)d_in[8];
  const float* A2 = (const float*)d_in[9];
  const float* b2 = (const float*)d_in[10];
  const float* p0 = (const float*)d_in[11];
  const float* p1 = (const float*)d_in[12];
  const float* p2 = (const float*)d_in[13];
  float* out = (float*)d_out;
  float* ws  = (float*)d_ws;

  const int N = in_sizes[0] / 128;

  hipMemsetAsync(d_out, 0, (size_t)out_size * sizeof(float), stream);
  setup_cg_par<<<12, 128, 0, stream>>>(ws);
  pack_weights<<<(PK_TOTAL + 255) / 256, 256, 0, stream>>>(A1, W0, A2, W1, W2, ws);
  const int blocks = (N + 15) / 16;

  const size_t yall_off = BUF_BASE;
  const size_t tw_off   = yall_off + (size_t)N * 288 * 2;
  const size_t need     = tw_off + (size_t)N * 288 * 2;

  if (ws_size >= need) {
    unsigned short* yall = (unsigned short*)((char*)d_ws + yall_off);
    unsigned short* tww  = (unsigned short*)((char*)d_ws + tw_off);
    gemm_full<<<blocks, 256, 0, stream>>>(x_scalar, x_sph, b1, b2, ws, yall, tww, N);
    tail_light<<<blocks, 256, 0, stream>>>(batch, p0, p1, p2, ws, yall, tww, out, N);
  } else {
    gemm_r8<<<blocks, 256, 0, stream>>>(x_scalar, x_sph, b1, b2, ws, N);
    tail_r8<<<blocks, 256, 0, stream>>>(x_sph, batch, W1, W2, p0, p1, p2, ws, out, N);
  }
}

// Round 13
// 197.930 us; speedup vs baseline: 4.4284x; 4.4284x over previous
//
#include <hip/hip_runtime.h>
#include <math.h>

// ---------------------------------------------------------------------------
// MegaCartTensorOut, R13: R11 + tail_light reads CG via SGPR (scalar) loads.
// R11: uncapped tail hoists ~200 cg LDS-broadcast values -> 256 VGPR, 9.5% occ.
// R12: launch_bounds(256,4) -> compiler under-allocated (64 VGPR) + 1.2GB spill.
// Fix: cg read DIRECTLY from global ws (uniform base + compile-time index ->
// s_load to SGPRs; no VGPR hoisting fodder, no cap needed). cg LDS staging
// and one barrier removed. All other code identical to passing R11.
// ---------------------------------------------------------------------------

#define N_CG_FLOATS 438

typedef short s16x8 __attribute__((ext_vector_type(8)));
typedef short s16x4 __attribute__((ext_vector_type(4)));
typedef float f32x4 __attribute__((ext_vector_type(4)));

// pk region (units: shorts, from byte 2048 of ws) — ends at byte 69632
#define PK_BYTE_OFF 2048
#define PK_A1 0       // 16 frags (K=128,N=64)
#define PK_W0 8192    // 8  frags (K=128,N=32), *1/sqrt(128)
#define PK_A2 12288   // 36 frags (K=64, N=288)
#define PK_W1 30720   // 4  frags (K=64, N=32), *0.125
#define PK_W2 32768   // 2  frags (K=32, N=32), *1/sqrt(32)
#define PK_TOTAL 33792

// intermediate buffers start ABOVE the pk region
#define BUF_BASE 131072
// fallback offsets
#define Y0_BYTE_OFF 131072
#define TW8_BYTE_OFF 3331072

__device__ __forceinline__ short f2bf(float f) {
  union { float f; unsigned u; } x; x.f = f;
  unsigned r = (x.u + 0x7FFFu + ((x.u >> 16) & 1u)) >> 16;
  return (short)r;
}
__device__ __forceinline__ float bf2f(unsigned short s) {
  union { unsigned u; float f; } x; x.u = ((unsigned)s) << 16;
  return x.f;
}

// ---------------- CG setup (verified rounds 1-12) ----------------------------

__device__ __forceinline__ double dfact(int n) {
  double r = 1.0;
  for (int i = 2; i <= n; ++i) r *= (double)i;
  return r;
}

__device__ __forceinline__ void u_elem(int l, int i, int j, double& re, double& im) {
  re = 0.0; im = 0.0;
  const int mr = i - l, mc = j - l;
  const double is2 = 0.70710678118654752440;
  if (mr == 0) { if (mc == 0) re = 1.0; }
  else if (mr > 0) {
    if (mc == mr) re = ((mr & 1) ? -1.0 : 1.0) * is2;
    else if (mc == -mr) re = is2;
  } else {
    int m = -mr;
    if (mc == m) im = -(((m & 1) ? -1.0 : 1.0)) * is2;
    else if (mc == -m) im = is2;
  }
}

__global__ void setup_cg_par(float* __restrict__ ws) {
  const int LAs[12] = {0, 1, 2, 1, 2, 0, 2, 1, 2, 1, 1, 1};
  const int LBs[12] = {0, 1, 2, 1, 2, 2, 0, 1, 2, 1, 1, 1};
  const int LOs[12] = {0, 0, 0, 1, 1, 2, 2, 2, 2, 0, 1, 2};
  const int OFF[12] = {0, 1, 10, 35, 62, 137, 162, 187, 232, 357, 366, 393};

  const int blk = blockIdx.x;
  const int l1 = LAs[blk], l2 = LBs[blk], l3 = LOs[blk];
  const double scale = (blk >= 9) ? sqrt(2.0 * l3 + 1.0) : 1.0;
  const int n1 = 2 * l1 + 1, n2 = 2 * l2 + 1, n3 = 2 * l3 + 1;
  const int nel = n1 * n2 * n3;
  const int t = threadIdx.x;

  __shared__ double Cs[125];
  __shared__ double Rre[125], Rim[125];
  __shared__ double s_inv;
  __shared__ int s_useRe;

  if (t < nel) {
    const int i3 = t % n3, i2 = (t / n3) % n2, i1 = t / (n3 * n2);
    const int m1 = i1 - l1, m2 = i2 - l2, m3 = i3 - l3;
    double val = 0.0;
    if (m1 + m2 == m3) {
      double pre = sqrt((2.0 * l3 + 1.0) * dfact(l1 + l2 - l3) * dfact(l1 - l2 + l3) *
                        dfact(-l1 + l2 + l3) / dfact(l1 + l2 + l3 + 1));
      pre *= sqrt(dfact(l3 + m3) * dfact(l3 - m3) * dfact(l1 - m1) * dfact(l1 + m1) *
                  dfact(l2 - m2) * dfact(l2 + m2));
      double s = 0.0;
      for (int k = 0; k <= l1 + l2 - l3; ++k) {
        int d1 = l1 + l2 - l3 - k, d2 = l1 - m1 - k, d3 = l2 + m2 - k;
        int d4 = l3 - l2 + m1 + k, d5 = l3 - l1 - m2 + k;
        if (d1 < 0 || d2 < 0 || d3 < 0 || d4 < 0 || d5 < 0) continue;
        double prod = dfact(k) * dfact(d1) * dfact(d2) * dfact(d3) * dfact(d4) * dfact(d5);
        s += ((k & 1) ? -1.0 : 1.0) / prod;
      }
      val = pre * s;
    }
    Cs[t] = val;
  }
  __syncthreads();

  if (t < nel) {
    const int c = t % n3, bb = (t / n3) % n2, a = t / (n3 * n2);
    double sr_ = 0.0, si_ = 0.0;
    for (int m = 0; m < n1; ++m) {
      double u1r, u1i;
      u_elem(l1, a, m, u1r, u1i);
      if (u1r == 0.0 && u1i == 0.0) continue;
      for (int nn = 0; nn < n2; ++nn) {
        double u2r, u2i;
        u_elem(l2, bb, nn, u2r, u2i);
        double t12r = u1r * u2r - u1i * u2i;
        double t12i = u1r * u2i + u1i * u2r;
        if (t12r == 0.0 && t12i == 0.0) continue;
        for (int o = 0; o < n3; ++o) {
          double cgv = Cs[(m * n2 + nn) * n3 + o];
          if (cgv == 0.0) continue;
          double u3r, u3i;
          u_elem(l3, c, o, u3r, u3i);
          sr_ += (t12r * u3r + t12i * u3i) * cgv;
          si_ += (t12i * u3r - t12r * u3i) * cgv;
        }
      }
    }
    Rre[t] = sr_;
    Rim[t] = si_;
  }
  __syncthreads();

  if (t == 0) {
    double maxRe = 0.0, maxIm = 0.0;
    for (int e = 0; e < nel; ++e) {
      maxRe = fmax(maxRe, fabs(Rre[e]));
      maxIm = fmax(maxIm, fabs(Rim[e]));
    }
    int useRe = (maxRe >= maxIm) ? 1 : 0;
    double nrm = 0.0;
    for (int e = 0; e < nel; ++e) {
      double vv = useRe ? Rre[e] : Rim[e];
      nrm += vv * vv;
    }
    s_useRe = useRe;
    s_inv = scale / sqrt(nrm);
  }
  __syncthreads();

  if (t < nel) {
    double vv = s_useRe ? Rre[t] : Rim[t];
    ws[OFF[blk] + t] = (float)(vv * s_inv);
  }
}

// ---------------- weight fragment packing ------------------------------------
__global__ void pack_weights(const float* __restrict__ A1, const float* __restrict__ W0,
                             const float* __restrict__ A2, const float* __restrict__ W1,
                             const float* __restrict__ W2, float* __restrict__ ws) {
  unsigned short* pk = (unsigned short*)((char*)ws + PK_BYTE_OFF);
  int e = blockIdx.x * 256 + threadIdx.x;
  if (e >= PK_TOTAL) return;
  const float* src;
  int Ncols, off;
  float scale;
  if (e < PK_W0)      { src = A1; Ncols = 64;  off = PK_A1; scale = 1.f; }
  else if (e < PK_A2) { src = W0; Ncols = 32;  off = PK_W0; scale = 0.08838834764831845f; }
  else if (e < PK_W1) { src = A2; Ncols = 288; off = PK_A2; scale = 1.f; }
  else if (e < PK_W2) { src = W1; Ncols = 32;  off = PK_W1; scale = 0.125f; }
  else                { src = W2; Ncols = 32;  off = PK_W2; scale = 0.17677669529663687f; }
  int local = e - off;
  int frag = local >> 9;
  int l = (local >> 3) & 63;
  int j = local & 7;
  int ntn = Ncols >> 4;
  int kt = frag / ntn, nt = frag - kt * ntn;
  int k = kt * 32 + 8 * (l >> 4) + j;
  int c = nt * 16 + (l & 15);
  pk[e] = (unsigned short)f2bf(src[k * Ncols + c] * scale);
}

// ---------------- shared helpers ---------------------------------------------

__device__ __forceinline__ s16x8 cvt8(const float* __restrict__ g) {
  float4 a = *(const float4*)g;
  float4 b = *(const float4*)(g + 4);
  s16x8 r;
  r[0] = f2bf(a.x); r[1] = f2bf(a.y); r[2] = f2bf(a.z); r[3] = f2bf(a.w);
  r[4] = f2bf(b.x); r[5] = f2bf(b.y); r[6] = f2bf(b.z); r[7] = f2bf(b.w);
  return r;
}

__device__ __forceinline__ void sw_wr8(char* sm, int base, int strideB, int r, int c0, s16x8 v) {
  int byte = base + r * strideB + c0 * 2;
  byte ^= (r & 7) << 4;
  *(s16x8*)(sm + byte) = v;
}
__device__ __forceinline__ s16x8 sw_lda16(const char* sm, int base, int strideB, int k0,
                                          int lane) {
  int r = lane & 15;
  int byte = base + r * strideB + (k0 + 8 * (lane >> 4)) * 2;
  byte ^= (r & 7) << 4;
  return *(const s16x8*)(sm + byte);
}

template <int LA, int LB, int LO>
__device__ __forceinline__ void tp_accum(const float* __restrict__ R, float w,
                                         const float* xa, const float* xb, float* sph) {
  constexpr int NA = 2 * LA + 1, NB = 2 * LB + 1, NC = 2 * LO + 1;
#pragma unroll
  for (int a = 0; a < NA; ++a) {
#pragma unroll
    for (int b = 0; b < NB; ++b) {
      float xab = xa[a] * xb[b] * w;
#pragma unroll
      for (int c = 0; c < NC; ++c) sph[c] = fmaf(xab, R[(a * NB + b) * NC + c], sph[c]);
    }
  }
}

// ================== FULL PATH: kernel A (all GEMMs) ==========================

#define FA_XS 0      // [16][128] bf16, 256B rows, swz
#define FA_SP 4096   // [16][128] bf16, 256B rows, swz
#define FA_H  8192   // [16][64]  bf16, 128B rows, swz
#define FA_P1 10240  // 3 planes x [16] rows x 128B, swz
#define FA_P2 16384  // 5 planes x [16] rows x 64B, swz
#define FA_SMEM 21504

__global__ __launch_bounds__(256) void gemm_full(
    const float* __restrict__ xs_g, const float* __restrict__ sp_g,
    const float* __restrict__ b1, const float* __restrict__ b2,
    const float* __restrict__ ws, unsigned short* __restrict__ yall,
    unsigned short* __restrict__ tww, int N) {
  __shared__ char sm[FA_SMEM];
  const unsigned short* pk = (const unsigned short*)((const char*)ws + PK_BYTE_OFF);

  const int t = threadIdx.x;
  const int b0 = blockIdx.x * 16;
  const int lane = t & 63;
  const int wid = t >> 6;

  // ---- staging: xs + sp0 (b128 swz writes)
  {
    int n = t >> 4, c0 = (t & 15) * 8;
    long nn = min((long)(b0 + n), (long)N - 1);
    sw_wr8(sm, FA_XS, 256, n, c0, cvt8(xs_g + nn * 128 + c0));
    sw_wr8(sm, FA_SP, 256, n, c0, cvt8(sp_g + nn * 480 + c0));
  }
  // ---- staging: l1 planes, chunk-local (4 u's per thread)
  {
    int n = t >> 4, uc = t & 15;
    long nn = min((long)(b0 + n), (long)N - 1);
    const float* g = sp_g + nn * 480 + 128 + uc * 12;
    float4 a0 = *(const float4*)(g), a1 = *(const float4*)(g + 4), a2 = *(const float4*)(g + 8);
    float fl[12] = {a0.x, a0.y, a0.z, a0.w, a1.x, a1.y, a1.z, a1.w, a2.x, a2.y, a2.z, a2.w};
#pragma unroll
    for (int m = 0; m < 3; ++m) {
      s16x4 e;
#pragma unroll
      for (int j = 0; j < 4; ++j) e[j] = f2bf(fl[j * 3 + m]);
      int byte = FA_P1 + m * 2048 + n * 128 + uc * 8;
      byte ^= (n & 7) << 4;
      *(s16x4*)(sm + byte) = e;
    }
  }
  // ---- staging: l2 planes (threads < 128, 4 u's per thread)
  if (t < 128) {
    int n = t >> 3, uc = t & 7;
    long nn = min((long)(b0 + n), (long)N - 1);
    const float* g = sp_g + nn * 480 + 320 + uc * 20;
    float4 a0 = *(const float4*)(g), a1 = *(const float4*)(g + 4), a2 = *(const float4*)(g + 8),
           a3 = *(const float4*)(g + 12), a4 = *(const float4*)(g + 16);
    float fl[20] = {a0.x, a0.y, a0.z, a0.w, a1.x, a1.y, a1.z, a1.w, a2.x, a2.y,
                    a2.z, a2.w, a3.x, a3.y, a3.z, a3.w, a4.x, a4.y, a4.z, a4.w};
#pragma unroll
    for (int m = 0; m < 5; ++m) {
      s16x4 e;
#pragma unroll
      for (int j = 0; j < 4; ++j) e[j] = f2bf(fl[j * 5 + m]);
      int byte = FA_P2 + m * 1024 + n * 64 + uc * 8;
      byte ^= (n & 7) << 4;
      *(s16x4*)(sm + byte) = e;
    }
  }
  __syncthreads();

  // ---- h = silu(xs @ A1 + b1); wave wid owns nt=wid -> LDS
  {
    f32x4 acc = {0.f, 0.f, 0.f, 0.f};
#pragma unroll
    for (int kt = 0; kt < 4; ++kt) {
      s16x8 a = sw_lda16(sm, FA_XS, 256, kt * 32, lane);
      s16x8 b = *(const s16x8*)(pk + PK_A1 + (((kt << 2) + wid) * 64 + lane) * 8);
      acc = __builtin_amdgcn_mfma_f32_16x16x32_bf16(a, b, acc, 0, 0, 0);
    }
    const int col = wid * 16 + (lane & 15);
    const int r0 = (lane >> 4) * 4;
    const float bb = b1[col];
#pragma unroll
    for (int q = 0; q < 4; ++q) {
      float hv = acc[q] + bb;
      hv = hv / (1.f + __expf(-hv));
      int r = r0 + q;
      int byte = FA_H + r * 128 + col * 2;
      byte ^= (r & 7) << 4;
      *(short*)(sm + byte) = f2bf(hv);
    }
  }

  const int r0 = (lane >> 4) * 4;
  // ---- y0 tiles (waves 0,1) -> yall cols 0..31
  if (wid < 2) {
    f32x4 acc = {0.f, 0.f, 0.f, 0.f};
#pragma unroll
    for (int kt = 0; kt < 4; ++kt) {
      s16x8 a = sw_lda16(sm, FA_SP, 256, kt * 32, lane);
      s16x8 b = *(const s16x8*)(pk + PK_W0 + (((kt << 1) + wid) * 64 + lane) * 8);
      acc = __builtin_amdgcn_mfma_f32_16x16x32_bf16(a, b, acc, 0, 0, 0);
    }
    const int col = wid * 16 + (lane & 15);
#pragma unroll
    for (int q = 0; q < 4; ++q)
      yall[(long)(b0 + r0 + q) * 288 + col] = (unsigned short)f2bf(acc[q]);
  }
  // ---- y1 tiles (6) -> yall cols 32..127
  for (int tl = wid; tl < 6; tl += 4) {
    const int m = tl >> 1, nt = tl & 1;
    f32x4 acc = {0.f, 0.f, 0.f, 0.f};
#pragma unroll
    for (int kt = 0; kt < 2; ++kt) {
      s16x8 a = sw_lda16(sm, FA_P1 + m * 2048, 128, kt * 32, lane);
      s16x8 b = *(const s16x8*)(pk + PK_W1 + (((kt << 1) + nt) * 64 + lane) * 8);
      acc = __builtin_amdgcn_mfma_f32_16x16x32_bf16(a, b, acc, 0, 0, 0);
    }
    const int col = 32 + m * 32 + nt * 16 + (lane & 15);
#pragma unroll
    for (int q = 0; q < 4; ++q)
      yall[(long)(b0 + r0 + q) * 288 + col] = (unsigned short)f2bf(acc[q]);
  }
  // ---- y2 tiles (10) -> yall cols 128..287
  for (int tl = wid; tl < 10; tl += 4) {
    const int m = tl >> 1, nt = tl & 1;
    f32x4 acc = {0.f, 0.f, 0.f, 0.f};
    {
      s16x8 a = sw_lda16(sm, FA_P2 + m * 1024, 64, 0, lane);
      s16x8 b = *(const s16x8*)(pk + PK_W2 + (nt * 64 + lane) * 8);
      acc = __builtin_amdgcn_mfma_f32_16x16x32_bf16(a, b, acc, 0, 0, 0);
    }
    const int col = 128 + m * 32 + nt * 16 + (lane & 15);
#pragma unroll
    for (int q = 0; q < 4; ++q)
      yall[(long)(b0 + r0 + q) * 288 + col] = (unsigned short)f2bf(acc[q]);
  }
  __syncthreads();  // H ready

  // ---- A2 tiles: tw = h @ A2 + b2 -> tww
  for (int tl = wid; tl < 18; tl += 4) {
    f32x4 acc = {0.f, 0.f, 0.f, 0.f};
#pragma unroll
    for (int kt = 0; kt < 2; ++kt) {
      s16x8 a = sw_lda16(sm, FA_H, 128, kt * 32, lane);
      s16x8 b = *(const s16x8*)(pk + PK_A2 + ((kt * 18 + tl) * 64 + lane) * 8);
      acc = __builtin_amdgcn_mfma_f32_16x16x32_bf16(a, b, acc, 0, 0, 0);
    }
    const int col = tl * 16 + (lane & 15);
    const float bb = b2[col];
#pragma unroll
    for (int q = 0; q < 4; ++q)
      tww[(long)(b0 + r0 + q) * 288 + col] = (unsigned short)f2bf(acc[q] + bb);
  }
}

// ================== FULL PATH: kernel B (light tail) =========================
// CG read straight from global ws: uniform base + compile-time offsets ->
// s_load into SGPRs (L2-hot, 1.7KB). No VGPR hoisting fodder; no cap.

__global__ __launch_bounds__(256) void tail_light(
    const int* __restrict__ batch, const float* __restrict__ p0,
    const float* __restrict__ p1, const float* __restrict__ p2,
    const float* __restrict__ cg, const unsigned short* __restrict__ yall,
    const unsigned short* __restrict__ tww, float* __restrict__ out, int N) {
  const int t = threadIdx.x;
  const int b0 = blockIdx.x * 16;

  const int v = t & 31;
  const int sl = t >> 5;
  const float invs32 = 0.17677669529663687f;
  const float k0c = invs32 / 3.0f;
  const float k1c = 1.7320508075688772f * invs32 / 2.0f;
  const float k2c = 2.23606797749979f * invs32 / 4.0f;
  const float c0 = k0c * p0[0], c1 = k0c * p0[1], c2 = k0c * p0[2];
  const float c3 = k1c * p1[0], c4 = k1c * p1[1];
  const float c5 = k2c * p2[0], c6 = k2c * p2[1], c7 = k2c * p2[2], c8 = k2c * p2[3];
  const float* qb0 = cg + 357;
  const float* qb1 = cg + 366;
  const float* qb2 = cg + 393;

#pragma unroll 1
  for (int r = 0; r < 2; ++r) {
    const int n = b0 + sl + 8 * r;
    const long nn = min((long)n, (long)N - 1);
    const unsigned short* yb = yall + nn * 288;
    const unsigned short* tb = tww + nn * 288;

    const float y0v = bf2f(yb[v]);
    float y1[3], y2[5];
#pragma unroll
    for (int m = 0; m < 3; ++m) y1[m] = bf2f(yb[32 + m * 32 + v]);
#pragma unroll
    for (int m = 0; m < 5; ++m) y2[m] = bf2f(yb[128 + m * 32 + v]);

    float s0 = y0v * y0v;
    float s1 = y1[0] * y1[0] + y1[1] * y1[1] + y1[2] * y1[2];
    float s2 = 0.f;
#pragma unroll
    for (int m = 0; m < 5; ++m) s2 = fmaf(y2[m], y2[m], s2);
#pragma unroll
    for (int msk = 16; msk >= 1; msk >>= 1) {
      s0 += __shfl_xor(s0, msk);
      s1 += __shfl_xor(s1, msk);
      s2 += __shfl_xor(s2, msk);
    }
    const float i0 = 1.0f / sqrtf(s0 * (1.0f / 32.0f) + 1e-5f);
    const float i1 = 1.0f / sqrtf(s1 * (1.0f / 96.0f) + 1e-5f);
    const float i2 = 1.0f / sqrtf(s2 * (1.0f / 160.0f) + 1e-5f);
    float xs0[1] = {y0v * i0};
    float xs1[3], xs2[5];
#pragma unroll
    for (int m = 0; m < 3; ++m) xs1[m] = y1[m] * i1;
#pragma unroll
    for (int m = 0; m < 5; ++m) xs2[m] = y2[m] * i2;

    float w9[9];
#pragma unroll
    for (int i = 0; i < 9; ++i) w9[i] = bf2f(tb[i * 32 + v]);

    float sph0[1] = {0.f};
    float sph1[3] = {0.f, 0.f, 0.f};
    float sph2[5] = {0.f, 0.f, 0.f, 0.f, 0.f};
    tp_accum<0, 0, 0>(cg + 0,   w9[0] * c0, xs0, xs0, sph0);
    tp_accum<1, 1, 0>(cg + 1,   w9[1] * c1, xs1, xs1, sph0);
    tp_accum<2, 2, 0>(cg + 10,  w9[2] * c2, xs2, xs2, sph0);
    tp_accum<1, 1, 1>(cg + 35,  w9[3] * c3, xs1, xs1, sph1);
    tp_accum<2, 2, 1>(cg + 62,  w9[4] * c4, xs2, xs2, sph1);
    tp_accum<0, 2, 2>(cg + 137, w9[5] * c5, xs0, xs2, sph2);
    tp_accum<2, 0, 2>(cg + 162, w9[6] * c6, xs2, xs0, sph2);
    tp_accum<1, 1, 2>(cg + 187, w9[7] * c7, xs1, xs1, sph2);
    tp_accum<2, 2, 2>(cg + 232, w9[8] * c8, xs2, xs2, sph2);

#pragma unroll
    for (int msk = 16; msk >= 1; msk >>= 1) {
      sph0[0] += __shfl_xor(sph0[0], msk);
#pragma unroll
      for (int m = 0; m < 3; ++m) sph1[m] += __shfl_xor(sph1[m], msk);
#pragma unroll
      for (int m = 0; m < 5; ++m) sph2[m] += __shfl_xor(sph2[m], msk);
    }

    if (v == 0 && n < N) {
      float* og = out + (long)batch[n] * 9;
#pragma unroll
      for (int i = 0; i < 3; ++i) {
#pragma unroll
        for (int j = 0; j < 3; ++j) {
          float val = sph0[0] * qb0[i * 3 + j];
#pragma unroll
          for (int m = 0; m < 3; ++m) val = fmaf(sph1[m], qb1[(i * 3 + j) * 3 + m], val);
#pragma unroll
          for (int m = 0; m < 5; ++m) val = fmaf(sph2[m], qb2[(i * 3 + j) * 5 + m], val);
          atomicAdd(&og[((i + 1) % 3) * 3 + ((j + 1) % 3)], val);
        }
      }
    }
  }
}

// ================== FALLBACK PATH: exact R8 kernels ==========================

#define A_XS_OFF 0
#define A_SP_OFF 4096
#define A_H_OFF 8192
#define A_SMEM 10240

__global__ __launch_bounds__(256) void gemm_r8(
    const float* __restrict__ xs_g, const float* __restrict__ sp_g,
    const float* __restrict__ b1, const float* __restrict__ b2,
    float* __restrict__ ws, int N) {
  __shared__ char sm[A_SMEM];
  const unsigned short* pk = (const unsigned short*)((const char*)ws + PK_BYTE_OFF);
  unsigned short* y0w = (unsigned short*)((char*)ws + Y0_BYTE_OFF);
  unsigned short* tww = (unsigned short*)((char*)ws + TW8_BYTE_OFF);

  const int t = threadIdx.x;
  const int b0 = blockIdx.x * 16;
  const int lane = t & 63;
  const int wid = t >> 6;

  {
    int n = t >> 4, c0 = (t & 15) * 8;
    long nn = min((long)(b0 + n), (long)N - 1);
    sw_wr8(sm, A_XS_OFF, 256, n, c0, cvt8(xs_g + nn * 128 + c0));
    sw_wr8(sm, A_SP_OFF, 256, n, c0, cvt8(sp_g + nn * 480 + c0));
  }
  __syncthreads();

  {
    f32x4 acc = {0.f, 0.f, 0.f, 0.f};
#pragma unroll
    for (int kt = 0; kt < 4; ++kt) {
      s16x8 a = sw_lda16(sm, A_XS_OFF, 256, kt * 32, lane);
      s16x8 b = *(const s16x8*)(pk + PK_A1 + (((kt << 2) + wid) * 64 + lane) * 8);
      acc = __builtin_amdgcn_mfma_f32_16x16x32_bf16(a, b, acc, 0, 0, 0);
    }
    const int col = wid * 16 + (lane & 15);
    const int r0 = (lane >> 4) * 4;
    const float bb = b1[col];
#pragma unroll
    for (int q = 0; q < 4; ++q) {
      float hv = acc[q] + bb;
      hv = hv / (1.f + __expf(-hv));
      int r = r0 + q;
      int byte = A_H_OFF + r * 128 + col * 2;
      byte ^= (r & 7) << 4;
      *(short*)(sm + byte) = f2bf(hv);
    }
  }

  if (wid >= 2) {
    f32x4 acc = {0.f, 0.f, 0.f, 0.f};
#pragma unroll
    for (int kt = 0; kt < 4; ++kt) {
      s16x8 a = sw_lda16(sm, A_SP_OFF, 256, kt * 32, lane);
      s16x8 b = *(const s16x8*)(pk + PK_W0 + (((kt << 1) + (wid - 2)) * 64 + lane) * 8);
      acc = __builtin_amdgcn_mfma_f32_16x16x32_bf16(a, b, acc, 0, 0, 0);
    }
    const int col = (wid - 2) * 16 + (lane & 15);
    const int r0 = (lane >> 4) * 4;
#pragma unroll
    for (int q = 0; q < 4; ++q)
      y0w[(long)(b0 + r0 + q) * 32 + col] = (unsigned short)f2bf(acc[q]);
  }
  __syncthreads();

#pragma unroll
  for (int i = 0; i < 5; ++i) {
    const int nt = wid + 4 * i;
    if (nt < 18) {
      f32x4 acc = {0.f, 0.f, 0.f, 0.f};
#pragma unroll
      for (int kt = 0; kt < 2; ++kt) {
        s16x8 a = sw_lda16(sm, A_H_OFF, 128, kt * 32, lane);
        s16x8 b = *(const s16x8*)(pk + PK_A2 + ((kt * 18 + nt) * 64 + lane) * 8);
        acc = __builtin_amdgcn_mfma_f32_16x16x32_bf16(a, b, acc, 0, 0, 0);
      }
      const int col = nt * 16 + (lane & 15);
      const int r0 = (lane >> 4) * 4;
      const float bb = b2[col];
#pragma unroll
      for (int q = 0; q < 4; ++q)
        tww[(long)(b0 + r0 + q) * 288 + col] = (unsigned short)f2bf(acc[q] + bb);
    }
  }
}

__global__ __launch_bounds__(256) void tail_r8(
    const float* __restrict__ sp_g, const int* __restrict__ batch,
    const float* __restrict__ W1g, const float* __restrict__ W2g,
    const float* __restrict__ p0, const float* __restrict__ p1,
    const float* __restrict__ p2, const float* __restrict__ ws,
    float* __restrict__ out, int N) {
  __shared__ __align__(16) float cg[N_CG_FLOATS];
  __shared__ __align__(16) float sp12[16 * 352];
  __shared__ __align__(16) float w12[3072];

  const unsigned short* y0w = (const unsigned short*)((const char*)ws + Y0_BYTE_OFF);
  const unsigned short* tww = (const unsigned short*)((const char*)ws + TW8_BYTE_OFF);

  const int t = threadIdx.x;
  const int b0 = blockIdx.x * 16;
  const int nb = min(16, N - b0);

  for (int i = t; i < N_CG_FLOATS; i += 256) cg[i] = ws[i];
  {
    float4* d = (float4*)sp12;
    for (int i = t; i < 16 * 88; i += 256) {
      int n = i / 88, j = i - n * 88;
      long nn = min((long)(b0 + n), (long)N - 1);
      d[i] = *(const float4*)(sp_g + nn * 480 + 128 + j * 4);
    }
    float4* w4 = (float4*)w12;
    for (int i = t; i < 768; i += 256) {
      float4 f;
      float scl;
      if (i < 512) { f = ((const float4*)W1g)[i]; scl = 0.125f; }
      else         { f = ((const float4*)W2g)[i - 512]; scl = 0.17677669529663687f; }
      float4 o;
      o.x = f.x * scl; o.y = f.y * scl; o.z = f.z * scl; o.w = f.w * scl;
      w4[i] = o;
    }
  }
  __syncthreads();

  const int v = t & 31;
  const int sl = t >> 5;
  const bool actA = (sl < nb);
  const bool actB = (sl + 8 < nb);
  const int rA = actA ? sl : 0;
  const int rB = actB ? (sl + 8) : 0;

  const float4* sA4 = (const float4*)(sp12 + rA * 352);
  const float4* sB4 = (const float4*)(sp12 + rB * 352);

  float y1A[3] = {0.f, 0.f, 0.f}, y1B[3] = {0.f, 0.f, 0.f};
#pragma unroll 4
  for (int q = 0; q < 16; ++q) {
    float4 a0 = sA4[q * 3], a1 = sA4[q * 3 + 1], a2 = sA4[q * 3 + 2];
    float4 c0_ = sB4[q * 3], c1_ = sB4[q * 3 + 1], c2_ = sB4[q * 3 + 2];
    float eA[12] = {a0.x, a0.y, a0.z, a0.w, a1.x, a1.y, a1.z, a1.w, a2.x, a2.y, a2.z, a2.w};
    float eB[12] = {c0_.x, c0_.y, c0_.z, c0_.w, c1_.x, c1_.y, c1_.z, c1_.w, c2_.x, c2_.y, c2_.z, c2_.w};
    float w = 0.f;
#pragma unroll
    for (int e = 0; e < 12; ++e) {
      if (e % 3 == 0) w = w12[(q * 4 + e / 3) * 32 + v];
      y1A[e % 3] = fmaf(eA[e], w, y1A[e % 3]);
      y1B[e % 3] = fmaf(eB[e], w, y1B[e % 3]);
    }
  }

  float y2A[5] = {0.f, 0.f, 0.f, 0.f, 0.f}, y2B[5] = {0.f, 0.f, 0.f, 0.f, 0.f};
#pragma unroll 2
  for (int q = 0; q < 8; ++q) {
    float4 a0 = sA4[48 + q * 5], a1 = sA4[48 + q * 5 + 1], a2 = sA4[48 + q * 5 + 2],
           a3 = sA4[48 + q * 5 + 3], a4 = sA4[48 + q * 5 + 4];
    float4 c0_ = sB4[48 + q * 5], c1_ = sB4[48 + q * 5 + 1], c2_ = sB4[48 + q * 5 + 2],
           c3_ = sB4[48 + q * 5 + 3], c4_ = sB4[48 + q * 5 + 4];
    float eA[20] = {a0.x, a0.y, a0.z, a0.w, a1.x, a1.y, a1.z, a1.w, a2.x, a2.y,
                    a2.z, a2.w, a3.x, a3.y, a3.z, a3.w, a4.x, a4.y, a4.z, a4.w};
    float eB[20] = {c0_.x, c0_.y, c0_.z, c0_.w, c1_.x, c1_.y, c1_.z, c1_.w, c2_.x, c2_.y,
                    c2_.z, c2_.w, c3_.x, c3_.y, c3_.z, c3_.w, c4_.x, c4_.y, c4_.z, c4_.w};
    float w = 0.f;
#pragma unroll
    for (int e = 0; e < 20; ++e) {
      if (e % 5 == 0) w = w12[2048 + (q * 4 + e / 5) * 32 + v];
      y2A[e % 5] = fmaf(eA[e], w, y2A[e % 5]);
      y2B[e % 5] = fmaf(eB[e], w, y2B[e % 5]);
    }
  }

  const float y0A = bf2f(y0w[(long)(b0 + rA) * 32 + v]);
  const float y0B = bf2f(y0w[(long)(b0 + rB) * 32 + v]);

  float s0A = y0A * y0A, s0B = y0B * y0B;
  float s1A = y1A[0] * y1A[0] + y1A[1] * y1A[1] + y1A[2] * y1A[2];
  float s1B = y1B[0] * y1B[0] + y1B[1] * y1B[1] + y1B[2] * y1B[2];
  float s2A = 0.f, s2B = 0.f;
#pragma unroll
  for (int m = 0; m < 5; ++m) { s2A = fmaf(y2A[m], y2A[m], s2A); s2B = fmaf(y2B[m], y2B[m], s2B); }
#pragma unroll
  for (int msk = 16; msk >= 1; msk >>= 1) {
    s0A += __shfl_xor(s0A, msk); s0B += __shfl_xor(s0B, msk);
    s1A += __shfl_xor(s1A, msk); s1B += __shfl_xor(s1B, msk);
    s2A += __shfl_xor(s2A, msk); s2B += __shfl_xor(s2B, msk);
  }
  const float i0A = 1.0f / sqrtf(s0A * (1.0f / 32.0f) + 1e-5f);
  const float i0B = 1.0f / sqrtf(s0B * (1.0f / 32.0f) + 1e-5f);
  const float i1A = 1.0f / sqrtf(s1A * (1.0f / 96.0f) + 1e-5f);
  const float i1B = 1.0f / sqrtf(s1B * (1.0f / 96.0f) + 1e-5f);
  const float i2A = 1.0f / sqrtf(s2A * (1.0f / 160.0f) + 1e-5f);
  const float i2B = 1.0f / sqrtf(s2B * (1.0f / 160.0f) + 1e-5f);

  float xs0A[1] = {y0A * i0A}, xs0B[1] = {y0B * i0B};
  float xs1A[3], xs1B[3], xs2A[5], xs2B[5];
#pragma unroll
  for (int m = 0; m < 3; ++m) { xs1A[m] = y1A[m] * i1A; xs1B[m] = y1B[m] * i1B; }
#pragma unroll
  for (int m = 0; m < 5; ++m) { xs2A[m] = y2A[m] * i2A; xs2B[m] = y2B[m] * i2B; }

  float wA[9], wB[9];
#pragma unroll
  for (int i = 0; i < 9; ++i) {
    wA[i] = bf2f(tww[(long)(b0 + rA) * 288 + i * 32 + v]);
    wB[i] = bf2f(tww[(long)(b0 + rB) * 288 + i * 32 + v]);
  }

  const float invs32 = 0.17677669529663687f;
  const float k0c = invs32 / 3.0f;
  const float k1c = 1.7320508075688772f * invs32 / 2.0f;
  const float k2c = 2.23606797749979f * invs32 / 4.0f;
  const float c0 = k0c * p0[0], c1 = k0c * p0[1], c2 = k0c * p0[2];
  const float c3 = k1c * p1[0], c4 = k1c * p1[1];
  const float c5 = k2c * p2[0], c6 = k2c * p2[1], c7 = k2c * p2[2], c8 = k2c * p2[3];

  float sph0A[1] = {0.f}, sph1A[3] = {0.f, 0.f, 0.f}, sph2A[5] = {0.f, 0.f, 0.f, 0.f, 0.f};
  float sph0B[1] = {0.f}, sph1B[3] = {0.f, 0.f, 0.f}, sph2B[5] = {0.f, 0.f, 0.f, 0.f, 0.f};

  tp_accum<0, 0, 0>(cg + 0,   wA[0] * c0, xs0A, xs0A, sph0A);
  tp_accum<0, 0, 0>(cg + 0,   wB[0] * c0, xs0B, xs0B, sph0B);
  tp_accum<1, 1, 0>(cg + 1,   wA[1] * c1, xs1A, xs1A, sph0A);
  tp_accum<1, 1, 0>(cg + 1,   wB[1] * c1, xs1B, xs1B, sph0B);
  tp_accum<2, 2, 0>(cg + 10,  wA[2] * c2, xs2A, xs2A, sph0A);
  tp_accum<2, 2, 0>(cg + 10,  wB[2] * c2, xs2B, xs2B, sph0B);
  tp_accum<1, 1, 1>(cg + 35,  wA[3] * c3, xs1A, xs1A, sph1A);
  tp_accum<1, 1, 1>(cg + 35,  wB[3] * c3, xs1B, xs1B, sph1B);
  tp_accum<2, 2, 1>(cg + 62,  wA[4] * c4, xs2A, xs2A, sph1A);
  tp_accum<2, 2, 1>(cg + 62,  wB[4] * c4, xs2B, xs2B, sph1B);
  tp_accum<0, 2, 2>(cg + 137, wA[5] * c5, xs0A, xs2A, sph2A);
  tp_accum<0, 2, 2>(cg + 137, wB[5] * c5, xs0B, xs2B, sph2B);
  tp_accum<2, 0, 2>(cg + 162, wA[6] * c6, xs2A, xs0A, sph2A);
  tp_accum<2, 0, 2>(cg + 162, wB[6] * c6, xs2B, xs0B, sph2B);
  tp_accum<1, 1, 2>(cg + 187, wA[7] * c7, xs1A, xs1A, sph2A);
  tp_accum<1, 1, 2>(cg + 187, wB[7] * c7, xs1B, xs1B, sph2B);
  tp_accum<2, 2, 2>(cg + 232, wA[8] * c8, xs2A, xs2A, sph2A);
  tp_accum<2, 2, 2>(cg + 232, wB[8] * c8, xs2B, xs2B, sph2B);

#pragma unroll
  for (int msk = 16; msk >= 1; msk >>= 1) {
    sph0A[0] += __shfl_xor(sph0A[0], msk);
    sph0B[0] += __shfl_xor(sph0B[0], msk);
#pragma unroll
    for (int m = 0; m < 3; ++m) {
      sph1A[m] += __shfl_xor(sph1A[m], msk);
      sph1B[m] += __shfl_xor(sph1B[m], msk);
    }
#pragma unroll
    for (int m = 0; m < 5; ++m) {
      sph2A[m] += __shfl_xor(sph2A[m], msk);
      sph2B[m] += __shfl_xor(sph2B[m], msk);
    }
  }

  if (v == 0) {
    const float* qb0 = cg + 357;
    const float* qb1 = cg + 366;
    const float* qb2 = cg + 393;
#pragma unroll
    for (int nd = 0; nd < 2; ++nd) {
      const bool act = nd ? actB : actA;
      if (!act) continue;
      const int n = b0 + (nd ? (sl + 8) : sl);
      const float* s0p = nd ? sph0B : sph0A;
      const float* s1p = nd ? sph1B : sph1A;
      const float* s2p = nd ? sph2B : sph2A;
      float* og = out + (long)batch[n] * 9;
#pragma unroll
      for (int i = 0; i < 3; ++i) {
#pragma unroll
        for (int j = 0; j < 3; ++j) {
          float val = s0p[0] * qb0[i * 3 + j];
#pragma unroll
          for (int m = 0; m < 3; ++m) val = fmaf(s1p[m], qb1[(i * 3 + j) * 3 + m], val);
#pragma unroll
          for (int m = 0; m < 5; ++m) val = fmaf(s2p[m], qb2[(i * 3 + j) * 5 + m], val);
          atomicAdd(&og[((i + 1) % 3) * 3 + ((j + 1) % 3)], val);
        }
      }
    }
  }
}

// ---------------------------------------------------------------------------

extern "C" void kernel_launch(void* const* d_in, const int* in_sizes, int n_in,
                              void* d_out, int out_size, void* d_ws, size_t ws_size,
                              hipStream_t stream) {
  const float* x_scalar = (const float*)d_in[0];
  const float* x_sph    = (const float*)d_in[1];
  const int*   batch    = (const int*)d_in[2];
  const float* W0 = (const float*)d_in[4];
  const float* W1 = (const float*)d_in[5];
  const float* W2 = (const float*)d_in[6];
  const float* A1 = (const float*)d_in[7];
  const float* b1 = (const float*)d_in[8];
  const float* A2 = (const float*)d_in[9];
  const float* b2 = (const float*)d_in[10];
  const float* p0 = (const float*)d_in[11];
  const float* p1 = (const float*)d_in[12];
  const float* p2 = (const float*)d_in[13];
  float* out = (float*)d_out;
  float* ws  = (float*)d_ws;

  const int N = in_sizes[0] / 128;

  hipMemsetAsync(d_out, 0, (size_t)out_size * sizeof(float), stream);
  setup_cg_par<<<12, 128, 0, stream>>>(ws);
  pack_weights<<<(PK_TOTAL + 255) / 256, 256, 0, stream>>>(A1, W0, A2, W1, W2, ws);
  const int blocks = (N + 15) / 16;

  const size_t yall_off = BUF_BASE;
  const size_t tw_off   = yall_off + (size_t)N * 288 * 2;
  const size_t need     = tw_off + (size_t)N * 288 * 2;

  if (ws_size >= need) {
    unsigned short* yall = (unsigned short*)((char*)d_ws + yall_off);
    unsigned short* tww  = (unsigned short*)((char*)d_ws + tw_off);
    gemm_full<<<blocks, 256, 0, stream>>>(x_scalar, x_sph, b1, b2, ws, yall, tww, N);
    tail_light<<<blocks, 256, 0, stream>>>(batch, p0, p1, p2, ws, yall, tww, out, N);
  } else {
    gemm_r8<<<blocks, 256, 0, stream>>>(x_scalar, x_sph, b1, b2, ws, N);
    tail_r8<<<blocks, 256, 0, stream>>>(x_sph, batch, W1, W2, p0, p1, p2, ws, out, N);
  }
}

// Round 14
// 111.843 us; speedup vs baseline: 7.8369x; 1.7697x over previous
//
#include <hip/hip_runtime.h>
#include <math.h>

// ---------------------------------------------------------------------------
// MegaCartTensorOut, R14: R13 + tail parallelism.
// R13: SGPR-CG fixed the allocator (VGPR 40, occ 52%, tail 134us). Remaining:
// 2 serial node-iters/block + lane-0-only cart epilogue. R14: 1 node per
// thread-slot (8 nodes/block, 2x blocks) and cart spread over 9 lanes (the
// butterfly leaves the full sums in ALL lanes). Everything else = R13.
// ---------------------------------------------------------------------------

#define N_CG_FLOATS 438

typedef short s16x8 __attribute__((ext_vector_type(8)));
typedef short s16x4 __attribute__((ext_vector_type(4)));
typedef float f32x4 __attribute__((ext_vector_type(4)));

// pk region (units: shorts, from byte 2048 of ws) — ends at byte 69632
#define PK_BYTE_OFF 2048
#define PK_A1 0       // 16 frags (K=128,N=64)
#define PK_W0 8192    // 8  frags (K=128,N=32), *1/sqrt(128)
#define PK_A2 12288   // 36 frags (K=64, N=288)
#define PK_W1 30720   // 4  frags (K=64, N=32), *0.125
#define PK_W2 32768   // 2  frags (K=32, N=32), *1/sqrt(32)
#define PK_TOTAL 33792

// intermediate buffers start ABOVE the pk region
#define BUF_BASE 131072
// fallback offsets
#define Y0_BYTE_OFF 131072
#define TW8_BYTE_OFF 3331072

__device__ __forceinline__ short f2bf(float f) {
  union { float f; unsigned u; } x; x.f = f;
  unsigned r = (x.u + 0x7FFFu + ((x.u >> 16) & 1u)) >> 16;
  return (short)r;
}
__device__ __forceinline__ float bf2f(unsigned short s) {
  union { unsigned u; float f; } x; x.u = ((unsigned)s) << 16;
  return x.f;
}

// ---------------- CG setup (verified rounds 1-13) ----------------------------

__device__ __forceinline__ double dfact(int n) {
  double r = 1.0;
  for (int i = 2; i <= n; ++i) r *= (double)i;
  return r;
}

__device__ __forceinline__ void u_elem(int l, int i, int j, double& re, double& im) {
  re = 0.0; im = 0.0;
  const int mr = i - l, mc = j - l;
  const double is2 = 0.70710678118654752440;
  if (mr == 0) { if (mc == 0) re = 1.0; }
  else if (mr > 0) {
    if (mc == mr) re = ((mr & 1) ? -1.0 : 1.0) * is2;
    else if (mc == -mr) re = is2;
  } else {
    int m = -mr;
    if (mc == m) im = -(((m & 1) ? -1.0 : 1.0)) * is2;
    else if (mc == -m) im = is2;
  }
}

__global__ void setup_cg_par(float* __restrict__ ws) {
  const int LAs[12] = {0, 1, 2, 1, 2, 0, 2, 1, 2, 1, 1, 1};
  const int LBs[12] = {0, 1, 2, 1, 2, 2, 0, 1, 2, 1, 1, 1};
  const int LOs[12] = {0, 0, 0, 1, 1, 2, 2, 2, 2, 0, 1, 2};
  const int OFF[12] = {0, 1, 10, 35, 62, 137, 162, 187, 232, 357, 366, 393};

  const int blk = blockIdx.x;
  const int l1 = LAs[blk], l2 = LBs[blk], l3 = LOs[blk];
  const double scale = (blk >= 9) ? sqrt(2.0 * l3 + 1.0) : 1.0;
  const int n1 = 2 * l1 + 1, n2 = 2 * l2 + 1, n3 = 2 * l3 + 1;
  const int nel = n1 * n2 * n3;
  const int t = threadIdx.x;

  __shared__ double Cs[125];
  __shared__ double Rre[125], Rim[125];
  __shared__ double s_inv;
  __shared__ int s_useRe;

  if (t < nel) {
    const int i3 = t % n3, i2 = (t / n3) % n2, i1 = t / (n3 * n2);
    const int m1 = i1 - l1, m2 = i2 - l2, m3 = i3 - l3;
    double val = 0.0;
    if (m1 + m2 == m3) {
      double pre = sqrt((2.0 * l3 + 1.0) * dfact(l1 + l2 - l3) * dfact(l1 - l2 + l3) *
                        dfact(-l1 + l2 + l3) / dfact(l1 + l2 + l3 + 1));
      pre *= sqrt(dfact(l3 + m3) * dfact(l3 - m3) * dfact(l1 - m1) * dfact(l1 + m1) *
                  dfact(l2 - m2) * dfact(l2 + m2));
      double s = 0.0;
      for (int k = 0; k <= l1 + l2 - l3; ++k) {
        int d1 = l1 + l2 - l3 - k, d2 = l1 - m1 - k, d3 = l2 + m2 - k;
        int d4 = l3 - l2 + m1 + k, d5 = l3 - l1 - m2 + k;
        if (d1 < 0 || d2 < 0 || d3 < 0 || d4 < 0 || d5 < 0) continue;
        double prod = dfact(k) * dfact(d1) * dfact(d2) * dfact(d3) * dfact(d4) * dfact(d5);
        s += ((k & 1) ? -1.0 : 1.0) / prod;
      }
      val = pre * s;
    }
    Cs[t] = val;
  }
  __syncthreads();

  if (t < nel) {
    const int c = t % n3, bb = (t / n3) % n2, a = t / (n3 * n2);
    double sr_ = 0.0, si_ = 0.0;
    for (int m = 0; m < n1; ++m) {
      double u1r, u1i;
      u_elem(l1, a, m, u1r, u1i);
      if (u1r == 0.0 && u1i == 0.0) continue;
      for (int nn = 0; nn < n2; ++nn) {
        double u2r, u2i;
        u_elem(l2, bb, nn, u2r, u2i);
        double t12r = u1r * u2r - u1i * u2i;
        double t12i = u1r * u2i + u1i * u2r;
        if (t12r == 0.0 && t12i == 0.0) continue;
        for (int o = 0; o < n3; ++o) {
          double cgv = Cs[(m * n2 + nn) * n3 + o];
          if (cgv == 0.0) continue;
          double u3r, u3i;
          u_elem(l3, c, o, u3r, u3i);
          sr_ += (t12r * u3r + t12i * u3i) * cgv;
          si_ += (t12i * u3r - t12r * u3i) * cgv;
        }
      }
    }
    Rre[t] = sr_;
    Rim[t] = si_;
  }
  __syncthreads();

  if (t == 0) {
    double maxRe = 0.0, maxIm = 0.0;
    for (int e = 0; e < nel; ++e) {
      maxRe = fmax(maxRe, fabs(Rre[e]));
      maxIm = fmax(maxIm, fabs(Rim[e]));
    }
    int useRe = (maxRe >= maxIm) ? 1 : 0;
    double nrm = 0.0;
    for (int e = 0; e < nel; ++e) {
      double vv = useRe ? Rre[e] : Rim[e];
      nrm += vv * vv;
    }
    s_useRe = useRe;
    s_inv = scale / sqrt(nrm);
  }
  __syncthreads();

  if (t < nel) {
    double vv = s_useRe ? Rre[t] : Rim[t];
    ws[OFF[blk] + t] = (float)(vv * s_inv);
  }
}

// ---------------- weight fragment packing ------------------------------------
__global__ void pack_weights(const float* __restrict__ A1, const float* __restrict__ W0,
                             const float* __restrict__ A2, const float* __restrict__ W1,
                             const float* __restrict__ W2, float* __restrict__ ws) {
  unsigned short* pk = (unsigned short*)((char*)ws + PK_BYTE_OFF);
  int e = blockIdx.x * 256 + threadIdx.x;
  if (e >= PK_TOTAL) return;
  const float* src;
  int Ncols, off;
  float scale;
  if (e < PK_W0)      { src = A1; Ncols = 64;  off = PK_A1; scale = 1.f; }
  else if (e < PK_A2) { src = W0; Ncols = 32;  off = PK_W0; scale = 0.08838834764831845f; }
  else if (e < PK_W1) { src = A2; Ncols = 288; off = PK_A2; scale = 1.f; }
  else if (e < PK_W2) { src = W1; Ncols = 32;  off = PK_W1; scale = 0.125f; }
  else                { src = W2; Ncols = 32;  off = PK_W2; scale = 0.17677669529663687f; }
  int local = e - off;
  int frag = local >> 9;
  int l = (local >> 3) & 63;
  int j = local & 7;
  int ntn = Ncols >> 4;
  int kt = frag / ntn, nt = frag - kt * ntn;
  int k = kt * 32 + 8 * (l >> 4) + j;
  int c = nt * 16 + (l & 15);
  pk[e] = (unsigned short)f2bf(src[k * Ncols + c] * scale);
}

// ---------------- shared helpers ---------------------------------------------

__device__ __forceinline__ s16x8 cvt8(const float* __restrict__ g) {
  float4 a = *(const float4*)g;
  float4 b = *(const float4*)(g + 4);
  s16x8 r;
  r[0] = f2bf(a.x); r[1] = f2bf(a.y); r[2] = f2bf(a.z); r[3] = f2bf(a.w);
  r[4] = f2bf(b.x); r[5] = f2bf(b.y); r[6] = f2bf(b.z); r[7] = f2bf(b.w);
  return r;
}

__device__ __forceinline__ void sw_wr8(char* sm, int base, int strideB, int r, int c0, s16x8 v) {
  int byte = base + r * strideB + c0 * 2;
  byte ^= (r & 7) << 4;
  *(s16x8*)(sm + byte) = v;
}
__device__ __forceinline__ s16x8 sw_lda16(const char* sm, int base, int strideB, int k0,
                                          int lane) {
  int r = lane & 15;
  int byte = base + r * strideB + (k0 + 8 * (lane >> 4)) * 2;
  byte ^= (r & 7) << 4;
  return *(const s16x8*)(sm + byte);
}

template <int LA, int LB, int LO>
__device__ __forceinline__ void tp_accum(const float* __restrict__ R, float w,
                                         const float* xa, const float* xb, float* sph) {
  constexpr int NA = 2 * LA + 1, NB = 2 * LB + 1, NC = 2 * LO + 1;
#pragma unroll
  for (int a = 0; a < NA; ++a) {
#pragma unroll
    for (int b = 0; b < NB; ++b) {
      float xab = xa[a] * xb[b] * w;
#pragma unroll
      for (int c = 0; c < NC; ++c) sph[c] = fmaf(xab, R[(a * NB + b) * NC + c], sph[c]);
    }
  }
}

// ================== FULL PATH: kernel A (all GEMMs) ==========================

#define FA_XS 0      // [16][128] bf16, 256B rows, swz
#define FA_SP 4096   // [16][128] bf16, 256B rows, swz
#define FA_H  8192   // [16][64]  bf16, 128B rows, swz
#define FA_P1 10240  // 3 planes x [16] rows x 128B, swz
#define FA_P2 16384  // 5 planes x [16] rows x 64B, swz
#define FA_SMEM 21504

__global__ __launch_bounds__(256) void gemm_full(
    const float* __restrict__ xs_g, const float* __restrict__ sp_g,
    const float* __restrict__ b1, const float* __restrict__ b2,
    const float* __restrict__ ws, unsigned short* __restrict__ yall,
    unsigned short* __restrict__ tww, int N) {
  __shared__ char sm[FA_SMEM];
  const unsigned short* pk = (const unsigned short*)((const char*)ws + PK_BYTE_OFF);

  const int t = threadIdx.x;
  const int b0 = blockIdx.x * 16;
  const int lane = t & 63;
  const int wid = t >> 6;

  // ---- staging: xs + sp0 (b128 swz writes)
  {
    int n = t >> 4, c0 = (t & 15) * 8;
    long nn = min((long)(b0 + n), (long)N - 1);
    sw_wr8(sm, FA_XS, 256, n, c0, cvt8(xs_g + nn * 128 + c0));
    sw_wr8(sm, FA_SP, 256, n, c0, cvt8(sp_g + nn * 480 + c0));
  }
  // ---- staging: l1 planes, chunk-local (4 u's per thread)
  {
    int n = t >> 4, uc = t & 15;
    long nn = min((long)(b0 + n), (long)N - 1);
    const float* g = sp_g + nn * 480 + 128 + uc * 12;
    float4 a0 = *(const float4*)(g), a1 = *(const float4*)(g + 4), a2 = *(const float4*)(g + 8);
    float fl[12] = {a0.x, a0.y, a0.z, a0.w, a1.x, a1.y, a1.z, a1.w, a2.x, a2.y, a2.z, a2.w};
#pragma unroll
    for (int m = 0; m < 3; ++m) {
      s16x4 e;
#pragma unroll
      for (int j = 0; j < 4; ++j) e[j] = f2bf(fl[j * 3 + m]);
      int byte = FA_P1 + m * 2048 + n * 128 + uc * 8;
      byte ^= (n & 7) << 4;
      *(s16x4*)(sm + byte) = e;
    }
  }
  // ---- staging: l2 planes (threads < 128, 4 u's per thread)
  if (t < 128) {
    int n = t >> 3, uc = t & 7;
    long nn = min((long)(b0 + n), (long)N - 1);
    const float* g = sp_g + nn * 480 + 320 + uc * 20;
    float4 a0 = *(const float4*)(g), a1 = *(const float4*)(g + 4), a2 = *(const float4*)(g + 8),
           a3 = *(const float4*)(g + 12), a4 = *(const float4*)(g + 16);
    float fl[20] = {a0.x, a0.y, a0.z, a0.w, a1.x, a1.y, a1.z, a1.w, a2.x, a2.y,
                    a2.z, a2.w, a3.x, a3.y, a3.z, a3.w, a4.x, a4.y, a4.z, a4.w};
#pragma unroll
    for (int m = 0; m < 5; ++m) {
      s16x4 e;
#pragma unroll
      for (int j = 0; j < 4; ++j) e[j] = f2bf(fl[j * 5 + m]);
      int byte = FA_P2 + m * 1024 + n * 64 + uc * 8;
      byte ^= (n & 7) << 4;
      *(s16x4*)(sm + byte) = e;
    }
  }
  __syncthreads();

  // ---- h = silu(xs @ A1 + b1); wave wid owns nt=wid -> LDS
  {
    f32x4 acc = {0.f, 0.f, 0.f, 0.f};
#pragma unroll
    for (int kt = 0; kt < 4; ++kt) {
      s16x8 a = sw_lda16(sm, FA_XS, 256, kt * 32, lane);
      s16x8 b = *(const s16x8*)(pk + PK_A1 + (((kt << 2) + wid) * 64 + lane) * 8);
      acc = __builtin_amdgcn_mfma_f32_16x16x32_bf16(a, b, acc, 0, 0, 0);
    }
    const int col = wid * 16 + (lane & 15);
    const int r0 = (lane >> 4) * 4;
    const float bb = b1[col];
#pragma unroll
    for (int q = 0; q < 4; ++q) {
      float hv = acc[q] + bb;
      hv = hv / (1.f + __expf(-hv));
      int r = r0 + q;
      int byte = FA_H + r * 128 + col * 2;
      byte ^= (r & 7) << 4;
      *(short*)(sm + byte) = f2bf(hv);
    }
  }

  const int r0 = (lane >> 4) * 4;
  // ---- y0 tiles (waves 0,1) -> yall cols 0..31
  if (wid < 2) {
    f32x4 acc = {0.f, 0.f, 0.f, 0.f};
#pragma unroll
    for (int kt = 0; kt < 4; ++kt) {
      s16x8 a = sw_lda16(sm, FA_SP, 256, kt * 32, lane);
      s16x8 b = *(const s16x8*)(pk + PK_W0 + (((kt << 1) + wid) * 64 + lane) * 8);
      acc = __builtin_amdgcn_mfma_f32_16x16x32_bf16(a, b, acc, 0, 0, 0);
    }
    const int col = wid * 16 + (lane & 15);
#pragma unroll
    for (int q = 0; q < 4; ++q)
      yall[(long)(b0 + r0 + q) * 288 + col] = (unsigned short)f2bf(acc[q]);
  }
  // ---- y1 tiles (6) -> yall cols 32..127
  for (int tl = wid; tl < 6; tl += 4) {
    const int m = tl >> 1, nt = tl & 1;
    f32x4 acc = {0.f, 0.f, 0.f, 0.f};
#pragma unroll
    for (int kt = 0; kt < 2; ++kt) {
      s16x8 a = sw_lda16(sm, FA_P1 + m * 2048, 128, kt * 32, lane);
      s16x8 b = *(const s16x8*)(pk + PK_W1 + (((kt << 1) + nt) * 64 + lane) * 8);
      acc = __builtin_amdgcn_mfma_f32_16x16x32_bf16(a, b, acc, 0, 0, 0);
    }
    const int col = 32 + m * 32 + nt * 16 + (lane & 15);
#pragma unroll
    for (int q = 0; q < 4; ++q)
      yall[(long)(b0 + r0 + q) * 288 + col] = (unsigned short)f2bf(acc[q]);
  }
  // ---- y2 tiles (10) -> yall cols 128..287
  for (int tl = wid; tl < 10; tl += 4) {
    const int m = tl >> 1, nt = tl & 1;
    f32x4 acc = {0.f, 0.f, 0.f, 0.f};
    {
      s16x8 a = sw_lda16(sm, FA_P2 + m * 1024, 64, 0, lane);
      s16x8 b = *(const s16x8*)(pk + PK_W2 + (nt * 64 + lane) * 8);
      acc = __builtin_amdgcn_mfma_f32_16x16x32_bf16(a, b, acc, 0, 0, 0);
    }
    const int col = 128 + m * 32 + nt * 16 + (lane & 15);
#pragma unroll
    for (int q = 0; q < 4; ++q)
      yall[(long)(b0 + r0 + q) * 288 + col] = (unsigned short)f2bf(acc[q]);
  }
  __syncthreads();  // H ready

  // ---- A2 tiles: tw = h @ A2 + b2 -> tww
  for (int tl = wid; tl < 18; tl += 4) {
    f32x4 acc = {0.f, 0.f, 0.f, 0.f};
#pragma unroll
    for (int kt = 0; kt < 2; ++kt) {
      s16x8 a = sw_lda16(sm, FA_H, 128, kt * 32, lane);
      s16x8 b = *(const s16x8*)(pk + PK_A2 + ((kt * 18 + tl) * 64 + lane) * 8);
      acc = __builtin_amdgcn_mfma_f32_16x16x32_bf16(a, b, acc, 0, 0, 0);
    }
    const int col = tl * 16 + (lane & 15);
    const float bb = b2[col];
#pragma unroll
    for (int q = 0; q < 4; ++q)
      tww[(long)(b0 + r0 + q) * 288 + col] = (unsigned short)f2bf(acc[q] + bb);
  }
}

// ================== FULL PATH: kernel B (light tail) =========================
// CG via uniform global loads (SGPR s_load; R13-verified: VGPR 40).
// R14: one node per thread-slot (8 nodes/block) + cart over 9 lanes.

__global__ __launch_bounds__(256) void tail_light(
    const int* __restrict__ batch, const float* __restrict__ p0,
    const float* __restrict__ p1, const float* __restrict__ p2,
    const float* __restrict__ cg, const unsigned short* __restrict__ yall,
    const unsigned short* __restrict__ tww, float* __restrict__ out, int N) {
  const int t = threadIdx.x;
  const int b0 = blockIdx.x * 8;

  const int v = t & 31;
  const int sl = t >> 5;
  const float invs32 = 0.17677669529663687f;
  const float k0c = invs32 / 3.0f;
  const float k1c = 1.7320508075688772f * invs32 / 2.0f;
  const float k2c = 2.23606797749979f * invs32 / 4.0f;
  const float c0 = k0c * p0[0], c1 = k0c * p0[1], c2 = k0c * p0[2];
  const float c3 = k1c * p1[0], c4 = k1c * p1[1];
  const float c5 = k2c * p2[0], c6 = k2c * p2[1], c7 = k2c * p2[2], c8 = k2c * p2[3];
  const float* qb0 = cg + 357;
  const float* qb1 = cg + 366;
  const float* qb2 = cg + 393;

  const int n = b0 + sl;
  const long nn = min((long)n, (long)N - 1);
  const unsigned short* yb = yall + nn * 288;
  const unsigned short* tb = tww + nn * 288;

  const float y0v = bf2f(yb[v]);
  float y1[3], y2[5];
#pragma unroll
  for (int m = 0; m < 3; ++m) y1[m] = bf2f(yb[32 + m * 32 + v]);
#pragma unroll
  for (int m = 0; m < 5; ++m) y2[m] = bf2f(yb[128 + m * 32 + v]);

  float s0 = y0v * y0v;
  float s1 = y1[0] * y1[0] + y1[1] * y1[1] + y1[2] * y1[2];
  float s2 = 0.f;
#pragma unroll
  for (int m = 0; m < 5; ++m) s2 = fmaf(y2[m], y2[m], s2);
#pragma unroll
  for (int msk = 16; msk >= 1; msk >>= 1) {
    s0 += __shfl_xor(s0, msk);
    s1 += __shfl_xor(s1, msk);
    s2 += __shfl_xor(s2, msk);
  }
  const float i0 = 1.0f / sqrtf(s0 * (1.0f / 32.0f) + 1e-5f);
  const float i1 = 1.0f / sqrtf(s1 * (1.0f / 96.0f) + 1e-5f);
  const float i2 = 1.0f / sqrtf(s2 * (1.0f / 160.0f) + 1e-5f);
  float xs0[1] = {y0v * i0};
  float xs1[3], xs2[5];
#pragma unroll
  for (int m = 0; m < 3; ++m) xs1[m] = y1[m] * i1;
#pragma unroll
  for (int m = 0; m < 5; ++m) xs2[m] = y2[m] * i2;

  float w9[9];
#pragma unroll
  for (int i = 0; i < 9; ++i) w9[i] = bf2f(tb[i * 32 + v]);

  float sph0[1] = {0.f};
  float sph1[3] = {0.f, 0.f, 0.f};
  float sph2[5] = {0.f, 0.f, 0.f, 0.f, 0.f};
  tp_accum<0, 0, 0>(cg + 0,   w9[0] * c0, xs0, xs0, sph0);
  tp_accum<1, 1, 0>(cg + 1,   w9[1] * c1, xs1, xs1, sph0);
  tp_accum<2, 2, 0>(cg + 10,  w9[2] * c2, xs2, xs2, sph0);
  tp_accum<1, 1, 1>(cg + 35,  w9[3] * c3, xs1, xs1, sph1);
  tp_accum<2, 2, 1>(cg + 62,  w9[4] * c4, xs2, xs2, sph1);
  tp_accum<0, 2, 2>(cg + 137, w9[5] * c5, xs0, xs2, sph2);
  tp_accum<2, 0, 2>(cg + 162, w9[6] * c6, xs2, xs0, sph2);
  tp_accum<1, 1, 2>(cg + 187, w9[7] * c7, xs1, xs1, sph2);
  tp_accum<2, 2, 2>(cg + 232, w9[8] * c8, xs2, xs2, sph2);

#pragma unroll
  for (int msk = 16; msk >= 1; msk >>= 1) {
    sph0[0] += __shfl_xor(sph0[0], msk);
#pragma unroll
    for (int m = 0; m < 3; ++m) sph1[m] += __shfl_xor(sph1[m], msk);
#pragma unroll
    for (int m = 0; m < 5; ++m) sph2[m] += __shfl_xor(sph2[m], msk);
  }

  // cart: lanes 0..8 each compute one (i,j) — butterfly left sums in ALL lanes
  if (v < 9 && n < N) {
    const int i = v / 3, j = v - 3 * i;
    float val = sph0[0] * qb0[v];
#pragma unroll
    for (int m = 0; m < 3; ++m) val = fmaf(sph1[m], qb1[v * 3 + m], val);
#pragma unroll
    for (int m = 0; m < 5; ++m) val = fmaf(sph2[m], qb2[v * 5 + m], val);
    float* og = out + (long)batch[n] * 9;
    atomicAdd(&og[((i + 1) % 3) * 3 + ((j + 1) % 3)], val);
  }
}

// ================== FALLBACK PATH: exact R8 kernels ==========================

#define A_XS_OFF 0
#define A_SP_OFF 4096
#define A_H_OFF 8192
#define A_SMEM 10240

__global__ __launch_bounds__(256) void gemm_r8(
    const float* __restrict__ xs_g, const float* __restrict__ sp_g,
    const float* __restrict__ b1, const float* __restrict__ b2,
    float* __restrict__ ws, int N) {
  __shared__ char sm[A_SMEM];
  const unsigned short* pk = (const unsigned short*)((const char*)ws + PK_BYTE_OFF);
  unsigned short* y0w = (unsigned short*)((char*)ws + Y0_BYTE_OFF);
  unsigned short* tww = (unsigned short*)((char*)ws + TW8_BYTE_OFF);

  const int t = threadIdx.x;
  const int b0 = blockIdx.x * 16;
  const int lane = t & 63;
  const int wid = t >> 6;

  {
    int n = t >> 4, c0 = (t & 15) * 8;
    long nn = min((long)(b0 + n), (long)N - 1);
    sw_wr8(sm, A_XS_OFF, 256, n, c0, cvt8(xs_g + nn * 128 + c0));
    sw_wr8(sm, A_SP_OFF, 256, n, c0, cvt8(sp_g + nn * 480 + c0));
  }
  __syncthreads();

  {
    f32x4 acc = {0.f, 0.f, 0.f, 0.f};
#pragma unroll
    for (int kt = 0; kt < 4; ++kt) {
      s16x8 a = sw_lda16(sm, A_XS_OFF, 256, kt * 32, lane);
      s16x8 b = *(const s16x8*)(pk + PK_A1 + (((kt << 2) + wid) * 64 + lane) * 8);
      acc = __builtin_amdgcn_mfma_f32_16x16x32_bf16(a, b, acc, 0, 0, 0);
    }
    const int col = wid * 16 + (lane & 15);
    const int r0 = (lane >> 4) * 4;
    const float bb = b1[col];
#pragma unroll
    for (int q = 0; q < 4; ++q) {
      float hv = acc[q] + bb;
      hv = hv / (1.f + __expf(-hv));
      int r = r0 + q;
      int byte = A_H_OFF + r * 128 + col * 2;
      byte ^= (r & 7) << 4;
      *(short*)(sm + byte) = f2bf(hv);
    }
  }

  if (wid >= 2) {
    f32x4 acc = {0.f, 0.f, 0.f, 0.f};
#pragma unroll
    for (int kt = 0; kt < 4; ++kt) {
      s16x8 a = sw_lda16(sm, A_SP_OFF, 256, kt * 32, lane);
      s16x8 b = *(const s16x8*)(pk + PK_W0 + (((kt << 1) + (wid - 2)) * 64 + lane) * 8);
      acc = __builtin_amdgcn_mfma_f32_16x16x32_bf16(a, b, acc, 0, 0, 0);
    }
    const int col = (wid - 2) * 16 + (lane & 15);
    const int r0 = (lane >> 4) * 4;
#pragma unroll
    for (int q = 0; q < 4; ++q)
      y0w[(long)(b0 + r0 + q) * 32 + col] = (unsigned short)f2bf(acc[q]);
  }
  __syncthreads();

#pragma unroll
  for (int i = 0; i < 5; ++i) {
    const int nt = wid + 4 * i;
    if (nt < 18) {
      f32x4 acc = {0.f, 0.f, 0.f, 0.f};
#pragma unroll
      for (int kt = 0; kt < 2; ++kt) {
        s16x8 a = sw_lda16(sm, A_H_OFF, 128, kt * 32, lane);
        s16x8 b = *(const s16x8*)(pk + PK_A2 + ((kt * 18 + nt) * 64 + lane) * 8);
        acc = __builtin_amdgcn_mfma_f32_16x16x32_bf16(a, b, acc, 0, 0, 0);
      }
      const int col = nt * 16 + (lane & 15);
      const int r0 = (lane >> 4) * 4;
      const float bb = b2[col];
#pragma unroll
      for (int q = 0; q < 4; ++q)
        tww[(long)(b0 + r0 + q) * 288 + col] = (unsigned short)f2bf(acc[q] + bb);
    }
  }
}

__global__ __launch_bounds__(256) void tail_r8(
    const float* __restrict__ sp_g, const int* __restrict__ batch,
    const float* __restrict__ W1g, const float* __restrict__ W2g,
    const float* __restrict__ p0, const float* __restrict__ p1,
    const float* __restrict__ p2, const float* __restrict__ ws,
    float* __restrict__ out, int N) {
  __shared__ __align__(16) float cg[N_CG_FLOATS];
  __shared__ __align__(16) float sp12[16 * 352];
  __shared__ __align__(16) float w12[3072];

  const unsigned short* y0w = (const unsigned short*)((const char*)ws + Y0_BYTE_OFF);
  const unsigned short* tww = (const unsigned short*)((const char*)ws + TW8_BYTE_OFF);

  const int t = threadIdx.x;
  const int b0 = blockIdx.x * 16;
  const int nb = min(16, N - b0);

  for (int i = t; i < N_CG_FLOATS; i += 256) cg[i] = ws[i];
  {
    float4* d = (float4*)sp12;
    for (int i = t; i < 16 * 88; i += 256) {
      int n = i / 88, j = i - n * 88;
      long nn = min((long)(b0 + n), (long)N - 1);
      d[i] = *(const float4*)(sp_g + nn * 480 + 128 + j * 4);
    }
    float4* w4 = (float4*)w12;
    for (int i = t; i < 768; i += 256) {
      float4 f;
      float scl;
      if (i < 512) { f = ((const float4*)W1g)[i]; scl = 0.125f; }
      else         { f = ((const float4*)W2g)[i - 512]; scl = 0.17677669529663687f; }
      float4 o;
      o.x = f.x * scl; o.y = f.y * scl; o.z = f.z * scl; o.w = f.w * scl;
      w4[i] = o;
    }
  }
  __syncthreads();

  const int v = t & 31;
  const int sl = t >> 5;
  const bool actA = (sl < nb);
  const bool actB = (sl + 8 < nb);
  const int rA = actA ? sl : 0;
  const int rB = actB ? (sl + 8) : 0;

  const float4* sA4 = (const float4*)(sp12 + rA * 352);
  const float4* sB4 = (const float4*)(sp12 + rB * 352);

  float y1A[3] = {0.f, 0.f, 0.f}, y1B[3] = {0.f, 0.f, 0.f};
#pragma unroll 4
  for (int q = 0; q < 16; ++q) {
    float4 a0 = sA4[q * 3], a1 = sA4[q * 3 + 1], a2 = sA4[q * 3 + 2];
    float4 c0_ = sB4[q * 3], c1_ = sB4[q * 3 + 1], c2_ = sB4[q * 3 + 2];
    float eA[12] = {a0.x, a0.y, a0.z, a0.w, a1.x, a1.y, a1.z, a1.w, a2.x, a2.y, a2.z, a2.w};
    float eB[12] = {c0_.x, c0_.y, c0_.z, c0_.w, c1_.x, c1_.y, c1_.z, c1_.w, c2_.x, c2_.y, c2_.z, c2_.w};
    float w = 0.f;
#pragma unroll
    for (int e = 0; e < 12; ++e) {
      if (e % 3 == 0) w = w12[(q * 4 + e / 3) * 32 + v];
      y1A[e % 3] = fmaf(eA[e], w, y1A[e % 3]);
      y1B[e % 3] = fmaf(eB[e], w, y1B[e % 3]);
    }
  }

  float y2A[5] = {0.f, 0.f, 0.f, 0.f, 0.f}, y2B[5] = {0.f, 0.f, 0.f, 0.f, 0.f};
#pragma unroll 2
  for (int q = 0; q < 8; ++q) {
    float4 a0 = sA4[48 + q * 5], a1 = sA4[48 + q * 5 + 1], a2 = sA4[48 + q * 5 + 2],
           a3 = sA4[48 + q * 5 + 3], a4 = sA4[48 + q * 5 + 4];
    float4 c0_ = sB4[48 + q * 5], c1_ = sB4[48 + q * 5 + 1], c2_ = sB4[48 + q * 5 + 2],
           c3_ = sB4[48 + q * 5 + 3], c4_ = sB4[48 + q * 5 + 4];
    float eA[20] = {a0.x, a0.y, a0.z, a0.w, a1.x, a1.y, a1.z, a1.w, a2.x, a2.y,
                    a2.z, a2.w, a3.x, a3.y, a3.z, a3.w, a4.x, a4.y, a4.z, a4.w};
    float eB[20] = {c0_.x, c0_.y, c0_.z, c0_.w, c1_.x, c1_.y, c1_.z, c1_.w, c2_.x, c2_.y,
                    c2_.z, c2_.w, c3_.x, c3_.y, c3_.z, c3_.w, c4_.x, c4_.y, c4_.z, c4_.w};
    float w = 0.f;
#pragma unroll
    for (int e = 0; e < 20; ++e) {
      if (e % 5 == 0) w = w12[2048 + (q * 4 + e / 5) * 32 + v];
      y2A[e % 5] = fmaf(eA[e], w, y2A[e % 5]);
      y2B[e % 5] = fmaf(eB[e], w, y2B[e % 5]);
    }
  }

  const float y0A = bf2f(y0w[(long)(b0 + rA) * 32 + v]);
  const float y0B = bf2f(y0w[(long)(b0 + rB) * 32 + v]);

  float s0A = y0A * y0A, s0B = y0B * y0B;
  float s1A = y1A[0] * y1A[0] + y1A[1] * y1A[1] + y1A[2] * y1A[2];
  float s1B = y1B[0] * y1B[0] + y1B[1] * y1B[1] + y1B[2] * y1B[2];
  float s2A = 0.f, s2B = 0.f;
#pragma unroll
  for (int m = 0; m < 5; ++m) { s2A = fmaf(y2A[m], y2A[m], s2A); s2B = fmaf(y2B[m], y2B[m], s2B); }
#pragma unroll
  for (int msk = 16; msk >= 1; msk >>= 1) {
    s0A += __shfl_xor(s0A, msk); s0B += __shfl_xor(s0B, msk);
    s1A += __shfl_xor(s1A, msk); s1B += __shfl_xor(s1B, msk);
    s2A += __shfl_xor(s2A, msk); s2B += __shfl_xor(s2B, msk);
  }
  const float i0A = 1.0f / sqrtf(s0A * (1.0f / 32.0f) + 1e-5f);
  const float i0B = 1.0f / sqrtf(s0B * (1.0f / 32.0f) + 1e-5f);
  const float i1A = 1.0f / sqrtf(s1A * (1.0f / 96.0f) + 1e-5f);
  const float i1B = 1.0f / sqrtf(s1B * (1.0f / 96.0f) + 1e-5f);
  const float i2A = 1.0f / sqrtf(s2A * (1.0f / 160.0f) + 1e-5f);
  const float i2B = 1.0f / sqrtf(s2B * (1.0f / 160.0f) + 1e-5f);

  float xs0A[1] = {y0A * i0A}, xs0B[1] = {y0B * i0B};
  float xs1A[3], xs1B[3], xs2A[5], xs2B[5];
#pragma unroll
  for (int m = 0; m < 3; ++m) { xs1A[m] = y1A[m] * i1A; xs1B[m] = y1B[m] * i1B; }
#pragma unroll
  for (int m = 0; m < 5; ++m) { xs2A[m] = y2A[m] * i2A; xs2B[m] = y2B[m] * i2B; }

  float wA[9], wB[9];
#pragma unroll
  for (int i = 0; i < 9; ++i) {
    wA[i] = bf2f(tww[(long)(b0 + rA) * 288 + i * 32 + v]);
    wB[i] = bf2f(tww[(long)(b0 + rB) * 288 + i * 32 + v]);
  }

  const float invs32 = 0.17677669529663687f;
  const float k0c = invs32 / 3.0f;
  const float k1c = 1.7320508075688772f * invs32 / 2.0f;
  const float k2c = 2.23606797749979f * invs32 / 4.0f;
  const float c0 = k0c * p0[0], c1 = k0c * p0[1], c2 = k0c * p0[2];
  const float c3 = k1c * p1[0], c4 = k1c * p1[1];
  const float c5 = k2c * p2[0], c6 = k2c * p2[1], c7 = k2c * p2[2], c8 = k2c * p2[3];

  float sph0A[1] = {0.f}, sph1A[3] = {0.f, 0.f, 0.f}, sph2A[5] = {0.f, 0.f, 0.f, 0.f, 0.f};
  float sph0B[1] = {0.f}, sph1B[3] = {0.f, 0.f, 0.f}, sph2B[5] = {0.f, 0.f, 0.f, 0.f, 0.f};

  tp_accum<0, 0, 0>(cg + 0,   wA[0] * c0, xs0A, xs0A, sph0A);
  tp_accum<0, 0, 0>(cg + 0,   wB[0] * c0, xs0B, xs0B, sph0B);
  tp_accum<1, 1, 0>(cg + 1,   wA[1] * c1, xs1A, xs1A, sph0A);
  tp_accum<1, 1, 0>(cg + 1,   wB[1] * c1, xs1B, xs1B, sph0B);
  tp_accum<2, 2, 0>(cg + 10,  wA[2] * c2, xs2A, xs2A, sph0A);
  tp_accum<2, 2, 0>(cg + 10,  wB[2] * c2, xs2B, xs2B, sph0B);
  tp_accum<1, 1, 1>(cg + 35,  wA[3] * c3, xs1A, xs1A, sph1A);
  tp_accum<1, 1, 1>(cg + 35,  wB[3] * c3, xs1B, xs1B, sph1B);
  tp_accum<2, 2, 1>(cg + 62,  wA[4] * c4, xs2A, xs2A, sph1A);
  tp_accum<2, 2, 1>(cg + 62,  wB[4] * c4, xs2B, xs2B, sph1B);
  tp_accum<0, 2, 2>(cg + 137, wA[5] * c5, xs0A, xs2A, sph2A);
  tp_accum<0, 2, 2>(cg + 137, wB[5] * c5, xs0B, xs2B, sph2B);
  tp_accum<2, 0, 2>(cg + 162, wA[6] * c6, xs2A, xs0A, sph2A);
  tp_accum<2, 0, 2>(cg + 162, wB[6] * c6, xs2B, xs0B, sph2B);
  tp_accum<1, 1, 2>(cg + 187, wA[7] * c7, xs1A, xs1A, sph2A);
  tp_accum<1, 1, 2>(cg + 187, wB[7] * c7, xs1B, xs1B, sph2B);
  tp_accum<2, 2, 2>(cg + 232, wA[8] * c8, xs2A, xs2A, sph2A);
  tp_accum<2, 2, 2>(cg + 232, wB[8] * c8, xs2B, xs2B, sph2B);

#pragma unroll
  for (int msk = 16; msk >= 1; msk >>= 1) {
    sph0A[0] += __shfl_xor(sph0A[0], msk);
    sph0B[0] += __shfl_xor(sph0B[0], msk);
#pragma unroll
    for (int m = 0; m < 3; ++m) {
      sph1A[m] += __shfl_xor(sph1A[m], msk);
      sph1B[m] += __shfl_xor(sph1B[m], msk);
    }
#pragma unroll
    for (int m = 0; m < 5; ++m) {
      sph2A[m] += __shfl_xor(sph2A[m], msk);
      sph2B[m] += __shfl_xor(sph2B[m], msk);
    }
  }

  if (v == 0) {
    const float* qb0 = cg + 357;
    const float* qb1 = cg + 366;
    const float* qb2 = cg + 393;
#pragma unroll
    for (int nd = 0; nd < 2; ++nd) {
      const bool act = nd ? actB : actA;
      if (!act) continue;
      const int n = b0 + (nd ? (sl + 8) : sl);
      const float* s0p = nd ? sph0B : sph0A;
      const float* s1p = nd ? sph1B : sph1A;
      const float* s2p = nd ? sph2B : sph2A;
      float* og = out + (long)batch[n] * 9;
#pragma unroll
      for (int i = 0; i < 3; ++i) {
#pragma unroll
        for (int j = 0; j < 3; ++j) {
          float val = s0p[0] * qb0[i * 3 + j];
#pragma unroll
          for (int m = 0; m < 3; ++m) val = fmaf(s1p[m], qb1[(i * 3 + j) * 3 + m], val);
#pragma unroll
          for (int m = 0; m < 5; ++m) val = fmaf(s2p[m], qb2[(i * 3 + j) * 5 + m], val);
          atomicAdd(&og[((i + 1) % 3) * 3 + ((j + 1) % 3)], val);
        }
      }
    }
  }
}

// ---------------------------------------------------------------------------

extern "C" void kernel_launch(void* const* d_in, const int* in_sizes, int n_in,
                              void* d_out, int out_size, void* d_ws, size_t ws_size,
                              hipStream_t stream) {
  const float* x_scalar = (const float*)d_in[0];
  const float* x_sph    = (const float*)d_in[1];
  const int*   batch    = (const int*)d_in[2];
  const float* W0 = (const float*)d_in[4];
  const float* W1 = (const float*)d_in[5];
  const float* W2 = (const float*)d_in[6];
  const float* A1 = (const float*)d_in[7];
  const float* b1 = (const float*)d_in[8];
  const float* A2 = (const float*)d_in[9];
  const float* b2 = (const float*)d_in[10];
  const float* p0 = (const float*)d_in[11];
  const float* p1 = (const float*)d_in[12];
  const float* p2 = (const float*)d_in[13];
  float* out = (float*)d_out;
  float* ws  = (float*)d_ws;

  const int N = in_sizes[0] / 128;

  hipMemsetAsync(d_out, 0, (size_t)out_size * sizeof(float), stream);
  setup_cg_par<<<12, 128, 0, stream>>>(ws);
  pack_weights<<<(PK_TOTAL + 255) / 256, 256, 0, stream>>>(A1, W0, A2, W1, W2, ws);
  const int blocks = (N + 15) / 16;

  const size_t yall_off = BUF_BASE;
  const size_t tw_off   = yall_off + (size_t)N * 288 * 2;
  const size_t need     = tw_off + (size_t)N * 288 * 2;

  if (ws_size >= need) {
    unsigned short* yall = (unsigned short*)((char*)d_ws + yall_off);
    unsigned short* tww  = (unsigned short*)((char*)d_ws + tw_off);
    gemm_full<<<blocks, 256, 0, stream>>>(x_scalar, x_sph, b1, b2, ws, yall, tww, N);
    const int tblocks = (N + 7) / 8;
    tail_light<<<tblocks, 256, 0, stream>>>(batch, p0, p1, p2, ws, yall, tww, out, N);
  } else {
    gemm_r8<<<blocks, 256, 0, stream>>>(x_scalar, x_sph, b1, b2, ws, N);
    tail_r8<<<blocks, 256, 0, stream>>>(x_sph, batch, W1, W2, p0, p1, p2, ws, out, N);
  }
}